// Round 1
// baseline (279.454 us; speedup 1.0000x reference)
//
#include <hip/hip_runtime.h>
#include <stdint.h>

typedef unsigned short ushort_t;
typedef __attribute__((ext_vector_type(8))) __bf16 bf16x8;
typedef __attribute__((ext_vector_type(4))) float f32x4;

__device__ __forceinline__ float b2f(ushort_t u) {
    unsigned v = ((unsigned)u) << 16;
    float f;
    __builtin_memcpy(&f, &v, 4);
    return f;
}

// RNE f32->bf16 via compiler cast (lowers to v_cvt_pk_bf16_f32 on gfx950;
// bit-identical rounding to the previous integer-RNE sequence, ~4 ops cheaper).
__device__ __forceinline__ ushort_t f2b(float f) {
    __bf16 h = (__bf16)f;
    return __builtin_bit_cast(ushort_t, h);
}

__device__ __forceinline__ void gl_lds16(const void* g, void* l) {
    __builtin_amdgcn_global_load_lds((const __attribute__((address_space(1))) void*)g,
                                     (__attribute__((address_space(3))) void*)l, 16, 0, 0);
}

// ---------------------------------------------------------------------------
// Fused preprocessing: w0/w1 bf16-cvt, sdat build, points2 transpose.
__global__ __launch_bounds__(256) void k_pre(const float* __restrict__ w0, ushort_t* __restrict__ w0b,
                                             const float* __restrict__ w1, ushort_t* __restrict__ w1b,
                                             const float* __restrict__ xyz2, float4* __restrict__ sdat,
                                             const float* __restrict__ points2, ushort_t* __restrict__ p2t) {
    int bid = blockIdx.x;
    int t = threadIdx.x;
    if (bid < 512) {
        int i = bid * 256 + t;
        w0b[i] = f2b(w0[i]);
    } else if (bid < 640) {
        int i = (bid - 512) * 256 + t;
        w1b[i] = f2b(w1[i]);
    } else if (bid < 704) {
        int bb = bid - 640;
        int b = bb & 15, by = bb >> 4;
        int s = by * 256 + t;
        const float* x2 = xyz2 + (size_t)b * 3 * 1024;
        float x = x2[s], y = x2[1024 + s], z = x2[2048 + s];
        float4 v;
        v.x = x; v.y = y; v.z = z;
        v.w = __fadd_rn(__fadd_rn(__fmul_rn(x, x), __fmul_rn(y, y)), __fmul_rn(z, z));
        sdat[(size_t)b * 1024 + s] = v;
    } else {
        int bb = bid - 704;
        int b = bb & 15, sy = bb >> 4;
        int s = sy * 64 + (t & 63);
        int g = t >> 6;
        const float* src = points2 + (size_t)b * 128 * 1024 + s;
        ushort_t* dst = p2t + ((size_t)b * 1024 + s) * 128;
#pragma unroll
        for (int i = 0; i < 4; ++i) {
            int cp = i * 4 + g;
            ushort_t tmp[8];
#pragma unroll
            for (int k = 0; k < 8; ++k) tmp[k] = f2b(src[(size_t)(cp * 8 + k) * 1024]);
            *(uint4*)(dst + cp * 8) = *(const uint4*)tmp;
        }
    }
}

// ---------------------------------------------------------------------------
// 3-NN + build X [65536][512] bf16. 32 queries/block, 8 slices x 128 points.
// sdat read directly from global: per half-wave uniform address -> L1/L2
// broadcast hit (16 KB/batch, fully cache-resident). LDS drops to 6.9 KB ->
// 8 blocks/CU. Distance EXPRESSION bit-identical to the passing version;
// distance top-3 updates use min/med3 (selects identical values), index
// updates keep the identical cmp/cndmask logic.
__global__ __launch_bounds__(256, 8) void k_interp(const float* __restrict__ xyz1,
                                                   const float4* __restrict__ sdat,
                                                   const float* __restrict__ points1,
                                                   const ushort_t* __restrict__ p2t,
                                                   ushort_t* __restrict__ X) {
    int b = blockIdx.x;
    int n0 = blockIdx.y * 32;
    int t = threadIdx.x;
    int tq = t & 31;        // query within block
    int slice = t >> 5;     // 0..7

    __shared__ float sD[256 * 3];
    __shared__ int   sI[256 * 3];
    __shared__ int   sidx[32 * 3];
    __shared__ float sw[32 * 3];

    int n = n0 + tq;
    float x = xyz1[((size_t)b * 3 + 0) * 4096 + n];
    float y = xyz1[((size_t)b * 3 + 1) * 4096 + n];
    float z = xyz1[((size_t)b * 3 + 2) * 4096 + n];
    float s1 = __fadd_rn(__fadd_rn(__fmul_rn(x, x), __fmul_rn(y, y)), __fmul_rn(z, z));

    float d0 = 1e30f, d1 = 1e30f, d2 = 1e30f;
    int i0 = 0, i1 = 0, i2 = 0;
    int sbeg = slice * 128;
    const float4* sdG = sdat + (size_t)b * 1024 + sbeg;
#pragma unroll 8
    for (int s = 0; s < 128; ++s) {
        float4 v = sdG[s];
        float dot = fmaf(z, v.z, fmaf(y, v.y, __fmul_rn(x, v.x)));
        float d = __fadd_rn(__fadd_rn(__fmul_rn(-2.0f, dot), s1), v.w);
        int si = sbeg + s;
        bool c0 = d < d0, c1 = d < d1, c2 = d < d2;
        // indices: identical logic to the verified version
        i2 = c1 ? i1 : (c2 ? si : i2);
        i1 = c0 ? i0 : (c1 ? si : i1);
        i0 = c0 ? si : i0;
        // distances: min/med3 forms select bit-identical values
        d2 = fminf(fmaxf(d, d1), d2);
        d1 = fminf(fmaxf(d, d0), d1);
        d0 = fminf(d, d0);
    }
    sD[t * 3 + 0] = d0; sD[t * 3 + 1] = d1; sD[t * 3 + 2] = d2;
    sI[t * 3 + 0] = i0; sI[t * 3 + 1] = i1; sI[t * 3 + 2] = i2;

    // points1 part: X[j][0:128] = bf16(points1[b][:, n])
    {
        const float* p1base = points1 + (size_t)b * 128 * 4096 + n0 + tq;
        ushort_t* dstbase = X + (size_t)(b * 4096 + n0 + tq) * 512;
#pragma unroll
        for (int i = 0; i < 2; ++i) {
            int piece = i * 8 + slice;
            ushort_t tmp[8];
#pragma unroll
            for (int k = 0; k < 8; ++k) tmp[k] = f2b(p1base[(size_t)(piece * 8 + k) * 4096]);
            *(uint4*)(dstbase + piece * 8) = *(const uint4*)tmp;
        }
    }
    __syncthreads();

    // merge: threads t<32 pick global top-3 of 24 candidates by lex (d, idx).
    if (t < 32) {
        int sel0 = -1, sel1 = -1;
        float seld[3]; int seli[3];
#pragma unroll
        for (int r = 0; r < 3; ++r) {
            float bd = 1e38f; int bi = 1 << 30;
            for (int k = 0; k < 24; ++k) {
                int s3 = (k * 0xAAAB) >> 17;    // k/3 for k<=23
                int rank = k - s3 * 3;
                int base = (s3 * 32 + t) * 3 + rank;
                float cd = sD[base];
                int ci = sI[base];
                bool excl = (ci == sel0) | (ci == sel1);
                bool better = (!excl) & ((cd < bd) | ((cd == bd) & (ci < bi)));
                if (better) { bd = cd; bi = ci; }
            }
            seld[r] = bd; seli[r] = bi;
            if (r == 0) sel0 = bi; else if (r == 1) sel1 = bi;
        }
        float r0 = 1.0f / (seld[0] + 1e-8f);
        float r1 = 1.0f / (seld[1] + 1e-8f);
        float r2 = 1.0f / (seld[2] + 1e-8f);
        float rs = r0 + r1 + r2;
        sw[t * 3 + 0] = r0 / rs; sw[t * 3 + 1] = r1 / rs; sw[t * 3 + 2] = r2 / rs;
        sidx[t * 3 + 0] = seli[0]; sidx[t * 3 + 1] = seli[1]; sidx[t * 3 + 2] = seli[2];
    }
    __syncthreads();

    // gather: 32 queries x 48 pieces = 1536 items
#pragma unroll
    for (int i = 0; i < 6; ++i) {
        int idx = i * 256 + t;
        int q = idx / 48;
        int rem = idx - q * 48;
        int r = rem >> 4;
        int piece = rem & 15;
        int si = sidx[q * 3 + r];
        float wt = sw[q * 3 + r];
        const ushort_t* src = p2t + ((size_t)b * 1024 + si) * 128 + piece * 8;
        uint4 raw = *(const uint4*)src;
        ushort_t* e = (ushort_t*)&raw;
        ushort_t outv[8];
#pragma unroll
        for (int k = 0; k < 8; ++k) outv[k] = f2b(wt * b2f(e[k]));
        ushort_t* dst = X + (size_t)(b * 4096 + n0 + q) * 512 + 128 + r * 128 + piece * 8;
        *(uint4*)dst = *(const uint4*)outv;
    }
}

// ---------------------------------------------------------------------------
// GEMM0: Y[j][o] = sum_k A[o][k]*Bt[j][k] + bias[o]
// LDS-staged coalesced epilogue + deterministic per-block stats partials.
__global__ __launch_bounds__(256) void k_gemm(const ushort_t* __restrict__ A,
                                              const ushort_t* __restrict__ Bt,
                                              const float* __restrict__ bias,
                                              ushort_t* __restrict__ Y,
                                              float* __restrict__ part_s,
                                              float* __restrict__ part_q,
                                              int Mtot, int K) {
    __shared__ __align__(16) char smem[35840];
    ushort_t* As = (ushort_t*)smem;
    ushort_t* Bs = (ushort_t*)(smem + 8192);
    ushort_t* sY = (ushort_t*)smem;          // 128 rows x 136 elems (epilogue)
    float* red_s = (float*)(smem + 34816);
    float* red_q = red_s + 128;

    int t = threadIdx.x;
    int m0 = blockIdx.x * 128;
    int j0 = blockIdx.y * 128;
    int wave = t >> 6, lane = t & 63;
    int wm = wave >> 1, wn = wave & 1;
    int l16 = lane & 15, quad = lane >> 4;

    if (t < 128) { red_s[t] = 0.f; red_q[t] = 0.f; }

    f32x4 acc[4][4] = {};

    int nk = K >> 5;
    for (int kt = 0; kt < nk; ++kt) {
#pragma unroll
        for (int c = 0; c < 2; ++c) {
            int idx = c * 256 + t;
            int row = idx >> 2, kc = idx & 3;
            gl_lds16(A + (size_t)(m0 + row) * K + kt * 32 + kc * 8, As + idx * 8);
            gl_lds16(Bt + (size_t)(j0 + row) * K + kt * 32 + kc * 8, Bs + idx * 8);
        }
        __syncthreads();

        bf16x8 af[4], bfr[4];
#pragma unroll
        for (int mi = 0; mi < 4; ++mi)
            af[mi] = *(const bf16x8*)(As + (wm * 64 + mi * 16 + l16) * 32 + quad * 8);
#pragma unroll
        for (int ni = 0; ni < 4; ++ni)
            bfr[ni] = *(const bf16x8*)(Bs + (wn * 64 + ni * 16 + l16) * 32 + quad * 8);
#pragma unroll
        for (int mi = 0; mi < 4; ++mi)
#pragma unroll
            for (int ni = 0; ni < 4; ++ni)
                acc[mi][ni] = __builtin_amdgcn_mfma_f32_16x16x32_bf16(af[mi], bfr[ni], acc[mi][ni], 0, 0, 0);
        __syncthreads();
    }

#pragma unroll
    for (int mi = 0; mi < 4; ++mi) {
        int obase = wm * 64 + mi * 16 + quad * 4;
        float bv[4];
#pragma unroll
        for (int r = 0; r < 4; ++r) bv[r] = bias[m0 + obase + r];
        float sr[4] = {0.f, 0.f, 0.f, 0.f}, qr[4] = {0.f, 0.f, 0.f, 0.f};
#pragma unroll
        for (int ni = 0; ni < 4; ++ni) {
            int j_local = wn * 64 + ni * 16 + l16;
            ushort4 pk;
            float v0 = acc[mi][ni][0] + bv[0];
            float v1 = acc[mi][ni][1] + bv[1];
            float v2 = acc[mi][ni][2] + bv[2];
            float v3 = acc[mi][ni][3] + bv[3];
            pk.x = f2b(v0); pk.y = f2b(v1); pk.z = f2b(v2); pk.w = f2b(v3);
            sr[0] += v0; qr[0] += v0 * v0;
            sr[1] += v1; qr[1] += v1 * v1;
            sr[2] += v2; qr[2] += v2 * v2;
            sr[3] += v3; qr[3] += v3 * v3;
            *(ushort4*)(sY + j_local * 136 + obase) = pk;
        }
#pragma unroll
        for (int r = 0; r < 4; ++r) {
            float s = sr[r], q = qr[r];
            s += __shfl_xor(s, 1); s += __shfl_xor(s, 2);
            s += __shfl_xor(s, 4); s += __shfl_xor(s, 8);
            q += __shfl_xor(q, 1); q += __shfl_xor(q, 2);
            q += __shfl_xor(q, 4); q += __shfl_xor(q, 8);
            if (l16 == 0) {
                atomicAdd(&red_s[obase + r], s);
                atomicAdd(&red_q[obase + r], q);
            }
        }
    }
    __syncthreads();

#pragma unroll
    for (int rep = 0; rep < 8; ++rep) {
        int idx = rep * 256 + t;
        int jl = idx >> 4;
        int o8 = idx & 15;
        uint4 vv = *(const uint4*)(sY + jl * 136 + o8 * 8);
        *(uint4*)(Y + (size_t)(j0 + jl) * Mtot + m0 + o8 * 8) = vv;
    }
    if (t < 128) {
        part_s[(size_t)blockIdx.y * Mtot + m0 + t] = red_s[t];
        part_q[(size_t)blockIdx.y * Mtot + m0 + t] = red_q[t];
    }
}

// ---------------------------------------------------------------------------
// GEMM1 with fused BN0+ReLU applied to the B (Y0) tiles at staging time.
// Math identical to the former k_act + k_gemm pair.
__global__ __launch_bounds__(256) void k_gemmf(const ushort_t* __restrict__ A,
                                               const ushort_t* __restrict__ Y0,
                                               const float* __restrict__ bias,
                                               const float* __restrict__ act_a,
                                               const float* __restrict__ act_b,
                                               ushort_t* __restrict__ Y,
                                               float* __restrict__ part_s,
                                               float* __restrict__ part_q,
                                               int Mtot, int K) {
    __shared__ __align__(16) char smem[35840];
    ushort_t* As = (ushort_t*)smem;
    ushort_t* Bs = (ushort_t*)(smem + 8192);
    float* sa = (float*)(smem + 16384);      // 256 floats (K<=256)
    float* sb = sa + 256;
    ushort_t* sY = (ushort_t*)smem;          // epilogue reuse
    float* red_s = (float*)(smem + 34816);
    float* red_q = red_s + 128;

    int t = threadIdx.x;
    int m0 = blockIdx.x * 128;
    int j0 = blockIdx.y * 128;
    int wave = t >> 6, lane = t & 63;
    int wm = wave >> 1, wn = wave & 1;
    int l16 = lane & 15, quad = lane >> 4;

    sa[t] = act_a[t]; sb[t] = act_b[t];
    if (t < 128) { red_s[t] = 0.f; red_q[t] = 0.f; }
    __syncthreads();

    f32x4 acc[4][4] = {};

    int nk = K >> 5;
    for (int kt = 0; kt < nk; ++kt) {
#pragma unroll
        for (int c = 0; c < 2; ++c) {
            int idx = c * 256 + t;
            int row = idx >> 2, kc = idx & 3;
            gl_lds16(A + (size_t)(m0 + row) * K + kt * 32 + kc * 8, As + idx * 8);
        }
#pragma unroll
        for (int c = 0; c < 2; ++c) {
            int idx = c * 256 + t;
            int row = idx >> 2, kc = idx & 3;
            int cbase = kt * 32 + kc * 8;
            uint4 raw = *(const uint4*)(Y0 + (size_t)(j0 + row) * K + cbase);
            ushort_t* e = (ushort_t*)&raw;
            ushort_t outv[8];
#pragma unroll
            for (int k = 0; k < 8; ++k) {
                float v = fmaxf(sa[cbase + k] * b2f(e[k]) + sb[cbase + k], 0.f);
                outv[k] = f2b(v);
            }
            *(uint4*)(Bs + idx * 8) = *(const uint4*)outv;
        }
        __syncthreads();

        bf16x8 af[4], bfr[4];
#pragma unroll
        for (int mi = 0; mi < 4; ++mi)
            af[mi] = *(const bf16x8*)(As + (wm * 64 + mi * 16 + l16) * 32 + quad * 8);
#pragma unroll
        for (int ni = 0; ni < 4; ++ni)
            bfr[ni] = *(const bf16x8*)(Bs + (wn * 64 + ni * 16 + l16) * 32 + quad * 8);
#pragma unroll
        for (int mi = 0; mi < 4; ++mi)
#pragma unroll
            for (int ni = 0; ni < 4; ++ni)
                acc[mi][ni] = __builtin_amdgcn_mfma_f32_16x16x32_bf16(af[mi], bfr[ni], acc[mi][ni], 0, 0, 0);
        __syncthreads();
    }

#pragma unroll
    for (int mi = 0; mi < 4; ++mi) {
        int obase = wm * 64 + mi * 16 + quad * 4;
        float bv[4];
#pragma unroll
        for (int r = 0; r < 4; ++r) bv[r] = bias[m0 + obase + r];
        float sr[4] = {0.f, 0.f, 0.f, 0.f}, qr[4] = {0.f, 0.f, 0.f, 0.f};
#pragma unroll
        for (int ni = 0; ni < 4; ++ni) {
            int j_local = wn * 64 + ni * 16 + l16;
            ushort4 pk;
            float v0 = acc[mi][ni][0] + bv[0];
            float v1 = acc[mi][ni][1] + bv[1];
            float v2 = acc[mi][ni][2] + bv[2];
            float v3 = acc[mi][ni][3] + bv[3];
            pk.x = f2b(v0); pk.y = f2b(v1); pk.z = f2b(v2); pk.w = f2b(v3);
            sr[0] += v0; qr[0] += v0 * v0;
            sr[1] += v1; qr[1] += v1 * v1;
            sr[2] += v2; qr[2] += v2 * v2;
            sr[3] += v3; qr[3] += v3 * v3;
            *(ushort4*)(sY + j_local * 136 + obase) = pk;
        }
#pragma unroll
        for (int r = 0; r < 4; ++r) {
            float s = sr[r], q = qr[r];
            s += __shfl_xor(s, 1); s += __shfl_xor(s, 2);
            s += __shfl_xor(s, 4); s += __shfl_xor(s, 8);
            q += __shfl_xor(q, 1); q += __shfl_xor(q, 2);
            q += __shfl_xor(q, 4); q += __shfl_xor(q, 8);
            if (l16 == 0) {
                atomicAdd(&red_s[obase + r], s);
                atomicAdd(&red_q[obase + r], q);
            }
        }
    }
    __syncthreads();

#pragma unroll
    for (int rep = 0; rep < 8; ++rep) {
        int idx = rep * 256 + t;
        int jl = idx >> 4;
        int o8 = idx & 15;
        uint4 vv = *(const uint4*)(sY + jl * 136 + o8 * 8);
        *(uint4*)(Y + (size_t)(j0 + jl) * Mtot + m0 + o8 * 8) = vv;
    }
    if (t < 128) {
        part_s[(size_t)blockIdx.y * Mtot + m0 + t] = red_s[t];
        part_q[(size_t)blockIdx.y * Mtot + m0 + t] = red_q[t];
    }
}

// ---------------------------------------------------------------------------
__global__ void k_bnfin(const float* __restrict__ part_s, const float* __restrict__ part_q,
                        int nby,
                        const float* __restrict__ gamma, const float* __restrict__ beta,
                        float* __restrict__ a, float* __restrict__ bb, int C, float inv_count) {
    int i = threadIdx.x;
    if (i < C) {
        float s = 0.f, q = 0.f;
#pragma unroll 8
        for (int by = 0; by < nby; ++by) {
            s += part_s[(size_t)by * C + i];
            q += part_q[(size_t)by * C + i];
        }
        float mean = s * inv_count;
        float var = q * inv_count - mean * mean;
        float sc = gamma[i] / sqrtf(var + 1e-5f);
        a[i] = sc;
        bb[i] = beta[i] - mean * sc;
    }
}

// ---------------------------------------------------------------------------
__global__ __launch_bounds__(256) void k_out(const ushort_t* __restrict__ Y1,
                                             const float* __restrict__ a,
                                             const float* __restrict__ bb,
                                             float* __restrict__ out) {
    __shared__ float sa[128], sb[128];
    int t = threadIdx.x;
    if (t < 128) { sa[t] = a[t]; sb[t] = bb[t]; }
    __syncthreads();
    int b = blockIdx.x;
    int nl = t & 127;
    int half = t >> 7;
    int n = blockIdx.y * 128 + nl;
    const uint4* src = (const uint4*)(Y1 + (size_t)(b * 4096 + n) * 128);
    float* dst = out + (size_t)b * 128 * 4096 + n;
    uint4 raw[8];
#pragma unroll
    for (int p = 0; p < 8; ++p) raw[p] = src[half * 8 + p];
    const ushort_t* e = (const ushort_t*)raw;
#pragma unroll
    for (int c = 0; c < 64; ++c) {
        int ch = half * 64 + c;
        float v = b2f(e[c]);
        v = fmaxf(sa[ch] * v + sb[ch], 0.f);
        dst[(size_t)ch * 4096] = v;
    }
}

// ---------------------------------------------------------------------------
extern "C" void kernel_launch(void* const* d_in, const int* in_sizes, int n_in,
                              void* d_out, int out_size, void* d_ws, size_t ws_size,
                              hipStream_t stream) {
    const float* xyz1    = (const float*)d_in[0];
    const float* xyz2    = (const float*)d_in[1];
    const float* points1 = (const float*)d_in[2];
    const float* points2 = (const float*)d_in[3];
    const float* w0      = (const float*)d_in[4];
    const float* b0      = (const float*)d_in[5];
    const float* gamma0  = (const float*)d_in[6];
    const float* beta0   = (const float*)d_in[7];
    const float* w1      = (const float*)d_in[8];
    const float* b1      = (const float*)d_in[9];
    const float* gamma1  = (const float*)d_in[10];
    const float* beta1   = (const float*)d_in[11];
    float* out = (float*)d_out;

    char* ws = (char*)d_ws;
    const size_t OFF_X    = 0;                       // 67108864
    const size_t OFF_Y0   = 67108864;                // 33554432
    const size_t OFF_Y1   = 100663296;               // 16777216
    const size_t OFF_P2T  = 117440512;               // 4194304
    const size_t OFF_W0B  = 121634816;               // 262144
    const size_t OFF_W1B  = 121896960;               // 65536
    const size_t OFF_AB   = 121962496;               // 3072
    const size_t OFF_SDAT = 121965568;               // 262144
    const size_t OFF_PS0  = 122227712;               // 524288
    const size_t OFF_PQ0  = 122752000;               // 524288
    const size_t OFF_PS1  = 123276288;               // 262144
    const size_t OFF_PQ1  = 123538432;               // 262144

    ushort_t* X    = (ushort_t*)(ws + OFF_X);
    ushort_t* Y0   = (ushort_t*)(ws + OFF_Y0);
    ushort_t* Y1   = (ushort_t*)(ws + OFF_Y1);
    ushort_t* p2t  = (ushort_t*)(ws + OFF_P2T);
    ushort_t* w0b  = (ushort_t*)(ws + OFF_W0B);
    ushort_t* w1b  = (ushort_t*)(ws + OFF_W1B);
    float* ab      = (float*)(ws + OFF_AB);
    float4* sdat   = (float4*)(ws + OFF_SDAT);
    float* ps0 = (float*)(ws + OFF_PS0);
    float* pq0 = (float*)(ws + OFF_PQ0);
    float* ps1 = (float*)(ws + OFF_PS1);
    float* pq1 = (float*)(ws + OFF_PQ1);
    float* a0 = ab;       float* bb0 = ab + 256;
    float* a1 = ab + 512; float* bb1 = ab + 640;

    k_pre<<<960, 256, 0, stream>>>(w0, w0b, w1, w1b, xyz2, sdat, points2, p2t);
    k_interp<<<dim3(16, 128), 256, 0, stream>>>(xyz1, sdat, points1, p2t, X);
    k_gemm<<<dim3(2, 512), 256, 0, stream>>>(w0b, X, b0, Y0, ps0, pq0, 256, 512);
    k_bnfin<<<1, 256, 0, stream>>>(ps0, pq0, 512, gamma0, beta0, a0, bb0, 256, 1.0f / 65536.0f);
    k_gemmf<<<dim3(1, 512), 256, 0, stream>>>(w1b, Y0, b1, a0, bb0, Y1, ps1, pq1, 128, 256);
    k_bnfin<<<1, 128, 0, stream>>>(ps1, pq1, 512, gamma1, beta1, a1, bb1, 128, 1.0f / 65536.0f);
    k_out<<<dim3(16, 32), 256, 0, stream>>>(Y1, a1, bb1, out);
}

// Round 2
// 264.551 us; speedup vs baseline: 1.0563x; 1.0563x over previous
//
#include <hip/hip_runtime.h>
#include <stdint.h>

typedef unsigned short ushort_t;
typedef __attribute__((ext_vector_type(8))) __bf16 bf16x8;
typedef __attribute__((ext_vector_type(4))) float f32x4;

__device__ __forceinline__ float b2f(ushort_t u) {
    unsigned v = ((unsigned)u) << 16;
    float f;
    __builtin_memcpy(&f, &v, 4);
    return f;
}

// RNE f32->bf16 via compiler cast (v_cvt_pk_bf16_f32 path on gfx950;
// identical RNE rounding to the old integer sequence, ~4 ops cheaper).
__device__ __forceinline__ ushort_t f2b(float f) {
    __bf16 h = (__bf16)f;
    return __builtin_bit_cast(ushort_t, h);
}

__device__ __forceinline__ void gl_lds16(const void* g, void* l) {
    __builtin_amdgcn_global_load_lds((const __attribute__((address_space(1))) void*)g,
                                     (__attribute__((address_space(3))) void*)l, 16, 0, 0);
}

// ---------------------------------------------------------------------------
// Fused preprocessing: w0/w1 bf16-cvt, sdat build, points2 transpose.
__global__ __launch_bounds__(256) void k_pre(const float* __restrict__ w0, ushort_t* __restrict__ w0b,
                                             const float* __restrict__ w1, ushort_t* __restrict__ w1b,
                                             const float* __restrict__ xyz2, float4* __restrict__ sdat,
                                             const float* __restrict__ points2, ushort_t* __restrict__ p2t) {
    int bid = blockIdx.x;
    int t = threadIdx.x;
    if (bid < 512) {
        int i = bid * 256 + t;
        w0b[i] = f2b(w0[i]);
    } else if (bid < 640) {
        int i = (bid - 512) * 256 + t;
        w1b[i] = f2b(w1[i]);
    } else if (bid < 704) {
        int bb = bid - 640;
        int b = bb & 15, by = bb >> 4;
        int s = by * 256 + t;
        const float* x2 = xyz2 + (size_t)b * 3 * 1024;
        float x = x2[s], y = x2[1024 + s], z = x2[2048 + s];
        float4 v;
        v.x = x; v.y = y; v.z = z;
        v.w = __fadd_rn(__fadd_rn(__fmul_rn(x, x), __fmul_rn(y, y)), __fmul_rn(z, z));
        sdat[(size_t)b * 1024 + s] = v;
    } else {
        int bb = bid - 704;
        int b = bb & 15, sy = bb >> 4;
        int s = sy * 64 + (t & 63);
        int g = t >> 6;
        const float* src = points2 + (size_t)b * 128 * 1024 + s;
        ushort_t* dst = p2t + ((size_t)b * 1024 + s) * 128;
#pragma unroll
        for (int i = 0; i < 4; ++i) {
            int cp = i * 4 + g;
            ushort_t tmp[8];
#pragma unroll
            for (int k = 0; k < 8; ++k) tmp[k] = f2b(src[(size_t)(cp * 8 + k) * 1024]);
            *(uint4*)(dst + cp * 8) = *(const uint4*)tmp;
        }
    }
}

// ---------------------------------------------------------------------------
// 3-NN + build X [65536][512] bf16. 32 queries/block, 8 slices x 128 points.
// sdat[b] staged to LDS once per block (scan reads are LDS half-wave
// broadcasts — this staging is load-bearing: removing it made the scan
// L2-latency-bound, 49.5 -> 62 us). Distance EXPRESSION bit-identical;
// distance top-3 updates use min/max (v_med3) forms selecting identical
// values; index updates keep identical cmp/cndmask logic.
__global__ __launch_bounds__(256) void k_interp(const float* __restrict__ xyz1,
                                                const float4* __restrict__ sdat,
                                                const float* __restrict__ points1,
                                                const ushort_t* __restrict__ p2t,
                                                ushort_t* __restrict__ X) {
    int b = blockIdx.x;
    int n0 = blockIdx.y * 32;
    int t = threadIdx.x;
    int tq = t & 31;        // query within block
    int slice = t >> 5;     // 0..7
    int wave = t >> 6, lane = t & 63;

    __shared__ __align__(16) float4 sP[1024];   // 16 KB: staged sdat[b]
    __shared__ float sD[256 * 3];
    __shared__ int   sI[256 * 3];
    __shared__ int   sidx[32 * 3];
    __shared__ float sw[32 * 3];

    // stage sdat[b] -> LDS (wave w loads points [w*256, w*256+256))
    {
        const float4* src = sdat + (size_t)b * 1024;
#pragma unroll
        for (int c = 0; c < 4; ++c) {
            int p = wave * 256 + c * 64 + lane;
            gl_lds16(src + p, (char*)sP + p * 16);
        }
    }

    int n = n0 + tq;
    float x = xyz1[((size_t)b * 3 + 0) * 4096 + n];
    float y = xyz1[((size_t)b * 3 + 1) * 4096 + n];
    float z = xyz1[((size_t)b * 3 + 2) * 4096 + n];
    float s1 = __fadd_rn(__fadd_rn(__fmul_rn(x, x), __fmul_rn(y, y)), __fmul_rn(z, z));

    __syncthreads();   // staging complete

    float d0 = 1e30f, d1 = 1e30f, d2 = 1e30f;
    int i0 = 0, i1 = 0, i2 = 0;
    int sbeg = slice * 128;
    const float4* sdL = sP + sbeg;
#pragma unroll 8
    for (int s = 0; s < 128; ++s) {
        float4 v = sdL[s];
        float dot = fmaf(z, v.z, fmaf(y, v.y, __fmul_rn(x, v.x)));
        float d = __fadd_rn(__fadd_rn(__fmul_rn(-2.0f, dot), s1), v.w);
        int si = sbeg + s;
        bool c0 = d < d0, c1 = d < d1, c2 = d < d2;
        // indices: identical logic to the verified version
        i2 = c1 ? i1 : (c2 ? si : i2);
        i1 = c0 ? i0 : (c1 ? si : i1);
        i0 = c0 ? si : i0;
        // distances: min/max (v_med3) forms select bit-identical values
        d2 = fminf(fmaxf(d, d1), d2);
        d1 = fminf(fmaxf(d, d0), d1);
        d0 = fminf(d, d0);
    }
    sD[t * 3 + 0] = d0; sD[t * 3 + 1] = d1; sD[t * 3 + 2] = d2;
    sI[t * 3 + 0] = i0; sI[t * 3 + 1] = i1; sI[t * 3 + 2] = i2;

    // points1 part: X[j][0:128] = bf16(points1[b][:, n])
    {
        const float* p1base = points1 + (size_t)b * 128 * 4096 + n0 + tq;
        ushort_t* dstbase = X + (size_t)(b * 4096 + n0 + tq) * 512;
#pragma unroll
        for (int i = 0; i < 2; ++i) {
            int piece = i * 8 + slice;
            ushort_t tmp[8];
#pragma unroll
            for (int k = 0; k < 8; ++k) tmp[k] = f2b(p1base[(size_t)(piece * 8 + k) * 4096]);
            *(uint4*)(dstbase + piece * 8) = *(const uint4*)tmp;
        }
    }
    __syncthreads();

    // merge: threads t<32 pick global top-3 of 24 candidates by lex (d, idx).
    if (t < 32) {
        int sel0 = -1, sel1 = -1;
        float seld[3]; int seli[3];
#pragma unroll
        for (int r = 0; r < 3; ++r) {
            float bd = 1e38f; int bi = 1 << 30;
            for (int k = 0; k < 24; ++k) {
                int s3 = (k * 0xAAAB) >> 17;    // k/3 for k<=23
                int rank = k - s3 * 3;
                int base = (s3 * 32 + t) * 3 + rank;
                float cd = sD[base];
                int ci = sI[base];
                bool excl = (ci == sel0) | (ci == sel1);
                bool better = (!excl) & ((cd < bd) | ((cd == bd) & (ci < bi)));
                if (better) { bd = cd; bi = ci; }
            }
            seld[r] = bd; seli[r] = bi;
            if (r == 0) sel0 = bi; else if (r == 1) sel1 = bi;
        }
        float r0 = 1.0f / (seld[0] + 1e-8f);
        float r1 = 1.0f / (seld[1] + 1e-8f);
        float r2 = 1.0f / (seld[2] + 1e-8f);
        float rs = r0 + r1 + r2;
        sw[t * 3 + 0] = r0 / rs; sw[t * 3 + 1] = r1 / rs; sw[t * 3 + 2] = r2 / rs;
        sidx[t * 3 + 0] = seli[0]; sidx[t * 3 + 1] = seli[1]; sidx[t * 3 + 2] = seli[2];
    }
    __syncthreads();

    // gather: 32 queries x 48 pieces = 1536 items
#pragma unroll
    for (int i = 0; i < 6; ++i) {
        int idx = i * 256 + t;
        int q = idx / 48;
        int rem = idx - q * 48;
        int r = rem >> 4;
        int piece = rem & 15;
        int si = sidx[q * 3 + r];
        float wt = sw[q * 3 + r];
        const ushort_t* src = p2t + ((size_t)b * 1024 + si) * 128 + piece * 8;
        uint4 raw = *(const uint4*)src;
        ushort_t* e = (ushort_t*)&raw;
        ushort_t outv[8];
#pragma unroll
        for (int k = 0; k < 8; ++k) outv[k] = f2b(wt * b2f(e[k]));
        ushort_t* dst = X + (size_t)(b * 4096 + n0 + q) * 512 + 128 + r * 128 + piece * 8;
        *(uint4*)dst = *(const uint4*)outv;
    }
}

// ---------------------------------------------------------------------------
// GEMM0: Y[j][o] = sum_k A[o][k]*Bt[j][k] + bias[o]
// LDS-staged coalesced epilogue + deterministic per-block stats partials.
__global__ __launch_bounds__(256) void k_gemm(const ushort_t* __restrict__ A,
                                              const ushort_t* __restrict__ Bt,
                                              const float* __restrict__ bias,
                                              ushort_t* __restrict__ Y,
                                              float* __restrict__ part_s,
                                              float* __restrict__ part_q,
                                              int Mtot, int K) {
    __shared__ __align__(16) char smem[35840];
    ushort_t* As = (ushort_t*)smem;
    ushort_t* Bs = (ushort_t*)(smem + 8192);
    ushort_t* sY = (ushort_t*)smem;          // 128 rows x 136 elems (epilogue)
    float* red_s = (float*)(smem + 34816);
    float* red_q = red_s + 128;

    int t = threadIdx.x;
    int m0 = blockIdx.x * 128;
    int j0 = blockIdx.y * 128;
    int wave = t >> 6, lane = t & 63;
    int wm = wave >> 1, wn = wave & 1;
    int l16 = lane & 15, quad = lane >> 4;

    if (t < 128) { red_s[t] = 0.f; red_q[t] = 0.f; }

    f32x4 acc[4][4] = {};

    int nk = K >> 5;
    for (int kt = 0; kt < nk; ++kt) {
#pragma unroll
        for (int c = 0; c < 2; ++c) {
            int idx = c * 256 + t;
            int row = idx >> 2, kc = idx & 3;
            gl_lds16(A + (size_t)(m0 + row) * K + kt * 32 + kc * 8, As + idx * 8);
            gl_lds16(Bt + (size_t)(j0 + row) * K + kt * 32 + kc * 8, Bs + idx * 8);
        }
        __syncthreads();

        bf16x8 af[4], bfr[4];
#pragma unroll
        for (int mi = 0; mi < 4; ++mi)
            af[mi] = *(const bf16x8*)(As + (wm * 64 + mi * 16 + l16) * 32 + quad * 8);
#pragma unroll
        for (int ni = 0; ni < 4; ++ni)
            bfr[ni] = *(const bf16x8*)(Bs + (wn * 64 + ni * 16 + l16) * 32 + quad * 8);
#pragma unroll
        for (int mi = 0; mi < 4; ++mi)
#pragma unroll
            for (int ni = 0; ni < 4; ++ni)
                acc[mi][ni] = __builtin_amdgcn_mfma_f32_16x16x32_bf16(af[mi], bfr[ni], acc[mi][ni], 0, 0, 0);
        __syncthreads();
    }

#pragma unroll
    for (int mi = 0; mi < 4; ++mi) {
        int obase = wm * 64 + mi * 16 + quad * 4;
        float bv[4];
#pragma unroll
        for (int r = 0; r < 4; ++r) bv[r] = bias[m0 + obase + r];
        float sr[4] = {0.f, 0.f, 0.f, 0.f}, qr[4] = {0.f, 0.f, 0.f, 0.f};
#pragma unroll
        for (int ni = 0; ni < 4; ++ni) {
            int j_local = wn * 64 + ni * 16 + l16;
            ushort4 pk;
            float v0 = acc[mi][ni][0] + bv[0];
            float v1 = acc[mi][ni][1] + bv[1];
            float v2 = acc[mi][ni][2] + bv[2];
            float v3 = acc[mi][ni][3] + bv[3];
            pk.x = f2b(v0); pk.y = f2b(v1); pk.z = f2b(v2); pk.w = f2b(v3);
            sr[0] += v0; qr[0] += v0 * v0;
            sr[1] += v1; qr[1] += v1 * v1;
            sr[2] += v2; qr[2] += v2 * v2;
            sr[3] += v3; qr[3] += v3 * v3;
            *(ushort4*)(sY + j_local * 136 + obase) = pk;
        }
#pragma unroll
        for (int r = 0; r < 4; ++r) {
            float s = sr[r], q = qr[r];
            s += __shfl_xor(s, 1); s += __shfl_xor(s, 2);
            s += __shfl_xor(s, 4); s += __shfl_xor(s, 8);
            q += __shfl_xor(q, 1); q += __shfl_xor(q, 2);
            q += __shfl_xor(q, 4); q += __shfl_xor(q, 8);
            if (l16 == 0) {
                atomicAdd(&red_s[obase + r], s);
                atomicAdd(&red_q[obase + r], q);
            }
        }
    }
    __syncthreads();

#pragma unroll
    for (int rep = 0; rep < 8; ++rep) {
        int idx = rep * 256 + t;
        int jl = idx >> 4;
        int o8 = idx & 15;
        uint4 vv = *(const uint4*)(sY + jl * 136 + o8 * 8);
        *(uint4*)(Y + (size_t)(j0 + jl) * Mtot + m0 + o8 * 8) = vv;
    }
    if (t < 128) {
        part_s[(size_t)blockIdx.y * Mtot + m0 + t] = red_s[t];
        part_q[(size_t)blockIdx.y * Mtot + m0 + t] = red_q[t];
    }
}

// ---------------------------------------------------------------------------
// GEMM1 with fused BN0+ReLU applied to the B (Y0) tiles at staging time.
// Math identical to the former k_act + k_gemm pair.
__global__ __launch_bounds__(256) void k_gemmf(const ushort_t* __restrict__ A,
                                               const ushort_t* __restrict__ Y0,
                                               const float* __restrict__ bias,
                                               const float* __restrict__ act_a,
                                               const float* __restrict__ act_b,
                                               ushort_t* __restrict__ Y,
                                               float* __restrict__ part_s,
                                               float* __restrict__ part_q,
                                               int Mtot, int K) {
    __shared__ __align__(16) char smem[35840];
    ushort_t* As = (ushort_t*)smem;
    ushort_t* Bs = (ushort_t*)(smem + 8192);
    float* sa = (float*)(smem + 16384);      // 256 floats (K<=256)
    float* sb = sa + 256;
    ushort_t* sY = (ushort_t*)smem;          // epilogue reuse
    float* red_s = (float*)(smem + 34816);
    float* red_q = red_s + 128;

    int t = threadIdx.x;
    int m0 = blockIdx.x * 128;
    int j0 = blockIdx.y * 128;
    int wave = t >> 6, lane = t & 63;
    int wm = wave >> 1, wn = wave & 1;
    int l16 = lane & 15, quad = lane >> 4;

    sa[t] = act_a[t]; sb[t] = act_b[t];
    if (t < 128) { red_s[t] = 0.f; red_q[t] = 0.f; }
    __syncthreads();

    f32x4 acc[4][4] = {};

    int nk = K >> 5;
    for (int kt = 0; kt < nk; ++kt) {
#pragma unroll
        for (int c = 0; c < 2; ++c) {
            int idx = c * 256 + t;
            int row = idx >> 2, kc = idx & 3;
            gl_lds16(A + (size_t)(m0 + row) * K + kt * 32 + kc * 8, As + idx * 8);
        }
#pragma unroll
        for (int c = 0; c < 2; ++c) {
            int idx = c * 256 + t;
            int row = idx >> 2, kc = idx & 3;
            int cbase = kt * 32 + kc * 8;
            uint4 raw = *(const uint4*)(Y0 + (size_t)(j0 + row) * K + cbase);
            ushort_t* e = (ushort_t*)&raw;
            ushort_t outv[8];
#pragma unroll
            for (int k = 0; k < 8; ++k) {
                float v = fmaxf(sa[cbase + k] * b2f(e[k]) + sb[cbase + k], 0.f);
                outv[k] = f2b(v);
            }
            *(uint4*)(Bs + idx * 8) = *(const uint4*)outv;
        }
        __syncthreads();

        bf16x8 af[4], bfr[4];
#pragma unroll
        for (int mi = 0; mi < 4; ++mi)
            af[mi] = *(const bf16x8*)(As + (wm * 64 + mi * 16 + l16) * 32 + quad * 8);
#pragma unroll
        for (int ni = 0; ni < 4; ++ni)
            bfr[ni] = *(const bf16x8*)(Bs + (wn * 64 + ni * 16 + l16) * 32 + quad * 8);
#pragma unroll
        for (int mi = 0; mi < 4; ++mi)
#pragma unroll
            for (int ni = 0; ni < 4; ++ni)
                acc[mi][ni] = __builtin_amdgcn_mfma_f32_16x16x32_bf16(af[mi], bfr[ni], acc[mi][ni], 0, 0, 0);
        __syncthreads();
    }

#pragma unroll
    for (int mi = 0; mi < 4; ++mi) {
        int obase = wm * 64 + mi * 16 + quad * 4;
        float bv[4];
#pragma unroll
        for (int r = 0; r < 4; ++r) bv[r] = bias[m0 + obase + r];
        float sr[4] = {0.f, 0.f, 0.f, 0.f}, qr[4] = {0.f, 0.f, 0.f, 0.f};
#pragma unroll
        for (int ni = 0; ni < 4; ++ni) {
            int j_local = wn * 64 + ni * 16 + l16;
            ushort4 pk;
            float v0 = acc[mi][ni][0] + bv[0];
            float v1 = acc[mi][ni][1] + bv[1];
            float v2 = acc[mi][ni][2] + bv[2];
            float v3 = acc[mi][ni][3] + bv[3];
            pk.x = f2b(v0); pk.y = f2b(v1); pk.z = f2b(v2); pk.w = f2b(v3);
            sr[0] += v0; qr[0] += v0 * v0;
            sr[1] += v1; qr[1] += v1 * v1;
            sr[2] += v2; qr[2] += v2 * v2;
            sr[3] += v3; qr[3] += v3 * v3;
            *(ushort4*)(sY + j_local * 136 + obase) = pk;
        }
#pragma unroll
        for (int r = 0; r < 4; ++r) {
            float s = sr[r], q = qr[r];
            s += __shfl_xor(s, 1); s += __shfl_xor(s, 2);
            s += __shfl_xor(s, 4); s += __shfl_xor(s, 8);
            q += __shfl_xor(q, 1); q += __shfl_xor(q, 2);
            q += __shfl_xor(q, 4); q += __shfl_xor(q, 8);
            if (l16 == 0) {
                atomicAdd(&red_s[obase + r], s);
                atomicAdd(&red_q[obase + r], q);
            }
        }
    }
    __syncthreads();

#pragma unroll
    for (int rep = 0; rep < 8; ++rep) {
        int idx = rep * 256 + t;
        int jl = idx >> 4;
        int o8 = idx & 15;
        uint4 vv = *(const uint4*)(sY + jl * 136 + o8 * 8);
        *(uint4*)(Y + (size_t)(j0 + jl) * Mtot + m0 + o8 * 8) = vv;
    }
    if (t < 128) {
        part_s[(size_t)blockIdx.y * Mtot + m0 + t] = red_s[t];
        part_q[(size_t)blockIdx.y * Mtot + m0 + t] = red_q[t];
    }
}

// ---------------------------------------------------------------------------
__global__ void k_bnfin(const float* __restrict__ part_s, const float* __restrict__ part_q,
                        int nby,
                        const float* __restrict__ gamma, const float* __restrict__ beta,
                        float* __restrict__ a, float* __restrict__ bb, int C, float inv_count) {
    int i = threadIdx.x;
    if (i < C) {
        float s = 0.f, q = 0.f;
#pragma unroll 8
        for (int by = 0; by < nby; ++by) {
            s += part_s[(size_t)by * C + i];
            q += part_q[(size_t)by * C + i];
        }
        float mean = s * inv_count;
        float var = q * inv_count - mean * mean;
        float sc = gamma[i] / sqrtf(var + 1e-5f);
        a[i] = sc;
        bb[i] = beta[i] - mean * sc;
    }
}

// ---------------------------------------------------------------------------
__global__ __launch_bounds__(256) void k_out(const ushort_t* __restrict__ Y1,
                                             const float* __restrict__ a,
                                             const float* __restrict__ bb,
                                             float* __restrict__ out) {
    __shared__ float sa[128], sb[128];
    int t = threadIdx.x;
    if (t < 128) { sa[t] = a[t]; sb[t] = bb[t]; }
    __syncthreads();
    int b = blockIdx.x;
    int nl = t & 127;
    int half = t >> 7;
    int n = blockIdx.y * 128 + nl;
    const uint4* src = (const uint4*)(Y1 + (size_t)(b * 4096 + n) * 128);
    float* dst = out + (size_t)b * 128 * 4096 + n;
    uint4 raw[8];
#pragma unroll
    for (int p = 0; p < 8; ++p) raw[p] = src[half * 8 + p];
    const ushort_t* e = (const ushort_t*)raw;
#pragma unroll
    for (int c = 0; c < 64; ++c) {
        int ch = half * 64 + c;
        float v = b2f(e[c]);
        v = fmaxf(sa[ch] * v + sb[ch], 0.f);
        dst[(size_t)ch * 4096] = v;
    }
}

// ---------------------------------------------------------------------------
extern "C" void kernel_launch(void* const* d_in, const int* in_sizes, int n_in,
                              void* d_out, int out_size, void* d_ws, size_t ws_size,
                              hipStream_t stream) {
    const float* xyz1    = (const float*)d_in[0];
    const float* xyz2    = (const float*)d_in[1];
    const float* points1 = (const float*)d_in[2];
    const float* points2 = (const float*)d_in[3];
    const float* w0      = (const float*)d_in[4];
    const float* b0      = (const float*)d_in[5];
    const float* gamma0  = (const float*)d_in[6];
    const float* beta0   = (const float*)d_in[7];
    const float* w1      = (const float*)d_in[8];
    const float* b1      = (const float*)d_in[9];
    const float* gamma1  = (const float*)d_in[10];
    const float* beta1   = (const float*)d_in[11];
    float* out = (float*)d_out;

    char* ws = (char*)d_ws;
    const size_t OFF_X    = 0;                       // 67108864
    const size_t OFF_Y0   = 67108864;                // 33554432
    const size_t OFF_Y1   = 100663296;               // 16777216
    const size_t OFF_P2T  = 117440512;               // 4194304
    const size_t OFF_W0B  = 121634816;               // 262144
    const size_t OFF_W1B  = 121896960;               // 65536
    const size_t OFF_AB   = 121962496;               // 3072
    const size_t OFF_SDAT = 121965568;               // 262144
    const size_t OFF_PS0  = 122227712;               // 524288
    const size_t OFF_PQ0  = 122752000;               // 524288
    const size_t OFF_PS1  = 123276288;               // 262144
    const size_t OFF_PQ1  = 123538432;               // 262144

    ushort_t* X    = (ushort_t*)(ws + OFF_X);
    ushort_t* Y0   = (ushort_t*)(ws + OFF_Y0);
    ushort_t* Y1   = (ushort_t*)(ws + OFF_Y1);
    ushort_t* p2t  = (ushort_t*)(ws + OFF_P2T);
    ushort_t* w0b  = (ushort_t*)(ws + OFF_W0B);
    ushort_t* w1b  = (ushort_t*)(ws + OFF_W1B);
    float* ab      = (float*)(ws + OFF_AB);
    float4* sdat   = (float4*)(ws + OFF_SDAT);
    float* ps0 = (float*)(ws + OFF_PS0);
    float* pq0 = (float*)(ws + OFF_PQ0);
    float* ps1 = (float*)(ws + OFF_PS1);
    float* pq1 = (float*)(ws + OFF_PQ1);
    float* a0 = ab;       float* bb0 = ab + 256;
    float* a1 = ab + 512; float* bb1 = ab + 640;

    k_pre<<<960, 256, 0, stream>>>(w0, w0b, w1, w1b, xyz2, sdat, points2, p2t);
    k_interp<<<dim3(16, 128), 256, 0, stream>>>(xyz1, sdat, points1, p2t, X);
    k_gemm<<<dim3(2, 512), 256, 0, stream>>>(w0b, X, b0, Y0, ps0, pq0, 256, 512);
    k_bnfin<<<1, 256, 0, stream>>>(ps0, pq0, 512, gamma0, beta0, a0, bb0, 256, 1.0f / 65536.0f);
    k_gemmf<<<dim3(1, 512), 256, 0, stream>>>(w1b, Y0, b1, a0, bb0, Y1, ps1, pq1, 128, 256);
    k_bnfin<<<1, 128, 0, stream>>>(ps1, pq1, 512, gamma1, beta1, a1, bb1, 128, 1.0f / 65536.0f);
    k_out<<<dim3(16, 32), 256, 0, stream>>>(Y1, a1, bb1, out);
}

// Round 3
// 220.839 us; speedup vs baseline: 1.2654x; 1.1979x over previous
//
#include <hip/hip_runtime.h>
#include <stdint.h>

typedef unsigned short ushort_t;
typedef __attribute__((ext_vector_type(8))) __bf16 bf16x8;
typedef __attribute__((ext_vector_type(4))) float f32x4;

__device__ __forceinline__ float b2f(ushort_t u) {
    unsigned v = ((unsigned)u) << 16;
    float f;
    __builtin_memcpy(&f, &v, 4);
    return f;
}

// RNE f32->bf16 via compiler cast (v_cvt path on gfx950; identical RNE
// rounding to the old integer sequence, ~4 ops cheaper).
__device__ __forceinline__ ushort_t f2b(float f) {
    __bf16 h = (__bf16)f;
    return __builtin_bit_cast(ushort_t, h);
}

__device__ __forceinline__ void gl_lds16(const void* g, void* l) {
    __builtin_amdgcn_global_load_lds((const __attribute__((address_space(1))) void*)g,
                                     (__attribute__((address_space(3))) void*)l, 16, 0, 0);
}

// ---------------------------------------------------------------------------
// Fused preprocessing: w0/w1 bf16-cvt, sdat build, points2 transpose.
__global__ __launch_bounds__(256) void k_pre(const float* __restrict__ w0, ushort_t* __restrict__ w0b,
                                             const float* __restrict__ w1, ushort_t* __restrict__ w1b,
                                             const float* __restrict__ xyz2, float4* __restrict__ sdat,
                                             const float* __restrict__ points2, ushort_t* __restrict__ p2t) {
    int bid = blockIdx.x;
    int t = threadIdx.x;
    if (bid < 512) {
        int i = bid * 256 + t;
        w0b[i] = f2b(w0[i]);
    } else if (bid < 640) {
        int i = (bid - 512) * 256 + t;
        w1b[i] = f2b(w1[i]);
    } else if (bid < 704) {
        int bb = bid - 640;
        int b = bb & 15, by = bb >> 4;
        int s = by * 256 + t;
        const float* x2 = xyz2 + (size_t)b * 3 * 1024;
        float x = x2[s], y = x2[1024 + s], z = x2[2048 + s];
        float4 v;
        v.x = x; v.y = y; v.z = z;
        v.w = __fadd_rn(__fadd_rn(__fmul_rn(x, x), __fmul_rn(y, y)), __fmul_rn(z, z));
        sdat[(size_t)b * 1024 + s] = v;
    } else {
        int bb = bid - 704;
        int b = bb & 15, sy = bb >> 4;
        int s = sy * 64 + (t & 63);
        int g = t >> 6;
        const float* src = points2 + (size_t)b * 128 * 1024 + s;
        ushort_t* dst = p2t + ((size_t)b * 1024 + s) * 128;
#pragma unroll
        for (int i = 0; i < 4; ++i) {
            int cp = i * 4 + g;
            ushort_t tmp[8];
#pragma unroll
            for (int k = 0; k < 8; ++k) tmp[k] = f2b(src[(size_t)(cp * 8 + k) * 1024]);
            *(uint4*)(dst + cp * 8) = *(const uint4*)tmp;
        }
    }
}

// ---------------------------------------------------------------------------
// 3-NN + build X [65536][512] bf16. 32 queries/block, 8 slices x 128 points.
// sdat[b] staged to LDS once per block (load-bearing: removing it made the
// scan L2-latency-bound, 49.5 -> 62 us). sidx/sw ALIAS the sP region (sP is
// dead after the scan; merge writes them after a barrier) -> LDS 22528 B ->
// 7 blocks/CU instead of 6. Distance expression bit-identical (fma fold of
// an exact *2 product); index cmp/cndmask logic unchanged.
__global__ __launch_bounds__(256) void k_interp(const float* __restrict__ xyz1,
                                                const float4* __restrict__ sdat,
                                                const float* __restrict__ points1,
                                                const ushort_t* __restrict__ p2t,
                                                ushort_t* __restrict__ X) {
    int b = blockIdx.x;
    int n0 = blockIdx.y * 32;
    int t = threadIdx.x;
    int tq = t & 31;        // query within block
    int slice = t >> 5;     // 0..7
    int wave = t >> 6, lane = t & 63;

    __shared__ __align__(16) char sbuf[16384];  // sP during scan; sidx/sw after
    float4* sP = (float4*)sbuf;                 // 1024 float4 staged sdat[b]
    int*   sidx = (int*)sbuf;                   // 32*3 ints   (after scan)
    float* sw   = (float*)(sbuf + 384);         // 32*3 floats (after scan)
    __shared__ float sD[256 * 3];
    __shared__ int   sI[256 * 3];

    // stage sdat[b] -> LDS (wave w loads points [w*256, w*256+256))
    {
        const float4* src = sdat + (size_t)b * 1024;
#pragma unroll
        for (int c = 0; c < 4; ++c) {
            int p = wave * 256 + c * 64 + lane;
            gl_lds16(src + p, sbuf + p * 16);
        }
    }

    int n = n0 + tq;
    float x = xyz1[((size_t)b * 3 + 0) * 4096 + n];
    float y = xyz1[((size_t)b * 3 + 1) * 4096 + n];
    float z = xyz1[((size_t)b * 3 + 2) * 4096 + n];
    float s1 = __fadd_rn(__fadd_rn(__fmul_rn(x, x), __fmul_rn(y, y)), __fmul_rn(z, z));

    __syncthreads();   // staging complete

    float d0 = 1e30f, d1 = 1e30f, d2 = 1e30f;
    int i0 = 0, i1 = 0, i2 = 0;
    int sbeg = slice * 128;
    const float4* sdL = sP + sbeg;
#pragma unroll 8
    for (int s = 0; s < 128; ++s) {
        float4 v = sdL[s];
        float dot = fmaf(z, v.z, fmaf(y, v.y, __fmul_rn(x, v.x)));
        // fmaf(-2,dot,s1) == add(mul(-2,dot),s1) bit-exactly: *2 is exact.
        float d = __fadd_rn(fmaf(-2.0f, dot, s1), v.w);
        int si = sbeg + s;
        bool c0 = d < d0, c1 = d < d1, c2 = d < d2;
        // indices: identical logic to the verified version
        i2 = c1 ? i1 : (c2 ? si : i2);
        i1 = c0 ? i0 : (c1 ? si : i1);
        i0 = c0 ? si : i0;
        // distances: min/max forms select bit-identical values
        d2 = fminf(fmaxf(d, d1), d2);
        d1 = fminf(fmaxf(d, d0), d1);
        d0 = fminf(d, d0);
    }
    sD[t * 3 + 0] = d0; sD[t * 3 + 1] = d1; sD[t * 3 + 2] = d2;
    sI[t * 3 + 0] = i0; sI[t * 3 + 1] = i1; sI[t * 3 + 2] = i2;

    // points1 part: X[j][0:128] = bf16(points1[b][:, n])
    {
        const float* p1base = points1 + (size_t)b * 128 * 4096 + n0 + tq;
        ushort_t* dstbase = X + (size_t)(b * 4096 + n0 + tq) * 512;
#pragma unroll
        for (int i = 0; i < 2; ++i) {
            int piece = i * 8 + slice;
            ushort_t tmp[8];
#pragma unroll
            for (int k = 0; k < 8; ++k) tmp[k] = f2b(p1base[(size_t)(piece * 8 + k) * 4096]);
            *(uint4*)(dstbase + piece * 8) = *(const uint4*)tmp;
        }
    }
    __syncthreads();   // scan + sD/sI complete; sP now dead

    // merge: threads t<32 pick global top-3 of 24 candidates by lex (d, idx).
    if (t < 32) {
        int sel0 = -1, sel1 = -1;
        float seld[3]; int seli[3];
#pragma unroll
        for (int r = 0; r < 3; ++r) {
            float bd = 1e38f; int bi = 1 << 30;
            for (int k = 0; k < 24; ++k) {
                int s3 = (k * 0xAAAB) >> 17;    // k/3 for k<=23
                int rank = k - s3 * 3;
                int base = (s3 * 32 + t) * 3 + rank;
                float cd = sD[base];
                int ci = sI[base];
                bool excl = (ci == sel0) | (ci == sel1);
                bool better = (!excl) & ((cd < bd) | ((cd == bd) & (ci < bi)));
                if (better) { bd = cd; bi = ci; }
            }
            seld[r] = bd; seli[r] = bi;
            if (r == 0) sel0 = bi; else if (r == 1) sel1 = bi;
        }
        float r0 = 1.0f / (seld[0] + 1e-8f);
        float r1 = 1.0f / (seld[1] + 1e-8f);
        float r2 = 1.0f / (seld[2] + 1e-8f);
        float rs = r0 + r1 + r2;
        sw[t * 3 + 0] = r0 / rs; sw[t * 3 + 1] = r1 / rs; sw[t * 3 + 2] = r2 / rs;
        sidx[t * 3 + 0] = seli[0]; sidx[t * 3 + 1] = seli[1]; sidx[t * 3 + 2] = seli[2];
    }
    __syncthreads();

    // gather: 32 queries x 48 pieces = 1536 items
#pragma unroll
    for (int i = 0; i < 6; ++i) {
        int idx = i * 256 + t;
        int q = idx / 48;
        int rem = idx - q * 48;
        int r = rem >> 4;
        int piece = rem & 15;
        int si = sidx[q * 3 + r];
        float wt = sw[q * 3 + r];
        const ushort_t* src = p2t + ((size_t)b * 1024 + si) * 128 + piece * 8;
        uint4 raw = *(const uint4*)src;
        ushort_t* e = (ushort_t*)&raw;
        ushort_t outv[8];
#pragma unroll
        for (int k = 0; k < 8; ++k) outv[k] = f2b(wt * b2f(e[k]));
        ushort_t* dst = X + (size_t)(b * 4096 + n0 + q) * 512 + 128 + r * 128 + piece * 8;
        *(uint4*)dst = *(const uint4*)outv;
    }
}

// ---------------------------------------------------------------------------
// GEMM0: Y[j][o] = sum_k A[o][k]*Bt[j][k] + bias[o]
// LDS-staged coalesced epilogue + deterministic per-block stats partials.
__global__ __launch_bounds__(256) void k_gemm(const ushort_t* __restrict__ A,
                                              const ushort_t* __restrict__ Bt,
                                              const float* __restrict__ bias,
                                              ushort_t* __restrict__ Y,
                                              float* __restrict__ part_s,
                                              float* __restrict__ part_q,
                                              int Mtot, int K) {
    __shared__ __align__(16) char smem[35840];
    ushort_t* As = (ushort_t*)smem;
    ushort_t* Bs = (ushort_t*)(smem + 8192);
    ushort_t* sY = (ushort_t*)smem;          // 128 rows x 136 elems (epilogue)
    float* red_s = (float*)(smem + 34816);
    float* red_q = red_s + 128;

    int t = threadIdx.x;
    int m0 = blockIdx.x * 128;
    int j0 = blockIdx.y * 128;
    int wave = t >> 6, lane = t & 63;
    int wm = wave >> 1, wn = wave & 1;
    int l16 = lane & 15, quad = lane >> 4;

    if (t < 128) { red_s[t] = 0.f; red_q[t] = 0.f; }

    f32x4 acc[4][4] = {};

    int nk = K >> 5;
    for (int kt = 0; kt < nk; ++kt) {
#pragma unroll
        for (int c = 0; c < 2; ++c) {
            int idx = c * 256 + t;
            int row = idx >> 2, kc = idx & 3;
            gl_lds16(A + (size_t)(m0 + row) * K + kt * 32 + kc * 8, As + idx * 8);
            gl_lds16(Bt + (size_t)(j0 + row) * K + kt * 32 + kc * 8, Bs + idx * 8);
        }
        __syncthreads();

        bf16x8 af[4], bfr[4];
#pragma unroll
        for (int mi = 0; mi < 4; ++mi)
            af[mi] = *(const bf16x8*)(As + (wm * 64 + mi * 16 + l16) * 32 + quad * 8);
#pragma unroll
        for (int ni = 0; ni < 4; ++ni)
            bfr[ni] = *(const bf16x8*)(Bs + (wn * 64 + ni * 16 + l16) * 32 + quad * 8);
#pragma unroll
        for (int mi = 0; mi < 4; ++mi)
#pragma unroll
            for (int ni = 0; ni < 4; ++ni)
                acc[mi][ni] = __builtin_amdgcn_mfma_f32_16x16x32_bf16(af[mi], bfr[ni], acc[mi][ni], 0, 0, 0);
        __syncthreads();
    }

#pragma unroll
    for (int mi = 0; mi < 4; ++mi) {
        int obase = wm * 64 + mi * 16 + quad * 4;
        float bv[4];
#pragma unroll
        for (int r = 0; r < 4; ++r) bv[r] = bias[m0 + obase + r];
        float sr[4] = {0.f, 0.f, 0.f, 0.f}, qr[4] = {0.f, 0.f, 0.f, 0.f};
#pragma unroll
        for (int ni = 0; ni < 4; ++ni) {
            int j_local = wn * 64 + ni * 16 + l16;
            ushort4 pk;
            float v0 = acc[mi][ni][0] + bv[0];
            float v1 = acc[mi][ni][1] + bv[1];
            float v2 = acc[mi][ni][2] + bv[2];
            float v3 = acc[mi][ni][3] + bv[3];
            pk.x = f2b(v0); pk.y = f2b(v1); pk.z = f2b(v2); pk.w = f2b(v3);
            sr[0] += v0; qr[0] += v0 * v0;
            sr[1] += v1; qr[1] += v1 * v1;
            sr[2] += v2; qr[2] += v2 * v2;
            sr[3] += v3; qr[3] += v3 * v3;
            *(ushort4*)(sY + j_local * 136 + obase) = pk;
        }
#pragma unroll
        for (int r = 0; r < 4; ++r) {
            float s = sr[r], q = qr[r];
            s += __shfl_xor(s, 1); s += __shfl_xor(s, 2);
            s += __shfl_xor(s, 4); s += __shfl_xor(s, 8);
            q += __shfl_xor(q, 1); q += __shfl_xor(q, 2);
            q += __shfl_xor(q, 4); q += __shfl_xor(q, 8);
            if (l16 == 0) {
                atomicAdd(&red_s[obase + r], s);
                atomicAdd(&red_q[obase + r], q);
            }
        }
    }
    __syncthreads();

#pragma unroll
    for (int rep = 0; rep < 8; ++rep) {
        int idx = rep * 256 + t;
        int jl = idx >> 4;
        int o8 = idx & 15;
        uint4 vv = *(const uint4*)(sY + jl * 136 + o8 * 8);
        *(uint4*)(Y + (size_t)(j0 + jl) * Mtot + m0 + o8 * 8) = vv;
    }
    if (t < 128) {
        part_s[(size_t)blockIdx.y * Mtot + m0 + t] = red_s[t];
        part_q[(size_t)blockIdx.y * Mtot + m0 + t] = red_q[t];
    }
}

// ---------------------------------------------------------------------------
// GEMM1 with fused BN0+ReLU applied to the B (Y0) tiles at staging time.
__global__ __launch_bounds__(256) void k_gemmf(const ushort_t* __restrict__ A,
                                               const ushort_t* __restrict__ Y0,
                                               const float* __restrict__ bias,
                                               const float* __restrict__ act_a,
                                               const float* __restrict__ act_b,
                                               ushort_t* __restrict__ Y,
                                               float* __restrict__ part_s,
                                               float* __restrict__ part_q,
                                               int Mtot, int K) {
    __shared__ __align__(16) char smem[35840];
    ushort_t* As = (ushort_t*)smem;
    ushort_t* Bs = (ushort_t*)(smem + 8192);
    float* sa = (float*)(smem + 16384);      // 256 floats (K<=256)
    float* sb = sa + 256;
    ushort_t* sY = (ushort_t*)smem;          // epilogue reuse
    float* red_s = (float*)(smem + 34816);
    float* red_q = red_s + 128;

    int t = threadIdx.x;
    int m0 = blockIdx.x * 128;
    int j0 = blockIdx.y * 128;
    int wave = t >> 6, lane = t & 63;
    int wm = wave >> 1, wn = wave & 1;
    int l16 = lane & 15, quad = lane >> 4;

    sa[t] = act_a[t]; sb[t] = act_b[t];
    if (t < 128) { red_s[t] = 0.f; red_q[t] = 0.f; }
    __syncthreads();

    f32x4 acc[4][4] = {};

    int nk = K >> 5;
    for (int kt = 0; kt < nk; ++kt) {
#pragma unroll
        for (int c = 0; c < 2; ++c) {
            int idx = c * 256 + t;
            int row = idx >> 2, kc = idx & 3;
            gl_lds16(A + (size_t)(m0 + row) * K + kt * 32 + kc * 8, As + idx * 8);
        }
#pragma unroll
        for (int c = 0; c < 2; ++c) {
            int idx = c * 256 + t;
            int row = idx >> 2, kc = idx & 3;
            int cbase = kt * 32 + kc * 8;
            uint4 raw = *(const uint4*)(Y0 + (size_t)(j0 + row) * K + cbase);
            ushort_t* e = (ushort_t*)&raw;
            ushort_t outv[8];
#pragma unroll
            for (int k = 0; k < 8; ++k) {
                float v = fmaxf(sa[cbase + k] * b2f(e[k]) + sb[cbase + k], 0.f);
                outv[k] = f2b(v);
            }
            *(uint4*)(Bs + idx * 8) = *(const uint4*)outv;
        }
        __syncthreads();

        bf16x8 af[4], bfr[4];
#pragma unroll
        for (int mi = 0; mi < 4; ++mi)
            af[mi] = *(const bf16x8*)(As + (wm * 64 + mi * 16 + l16) * 32 + quad * 8);
#pragma unroll
        for (int ni = 0; ni < 4; ++ni)
            bfr[ni] = *(const bf16x8*)(Bs + (wn * 64 + ni * 16 + l16) * 32 + quad * 8);
#pragma unroll
        for (int mi = 0; mi < 4; ++mi)
#pragma unroll
            for (int ni = 0; ni < 4; ++ni)
                acc[mi][ni] = __builtin_amdgcn_mfma_f32_16x16x32_bf16(af[mi], bfr[ni], acc[mi][ni], 0, 0, 0);
        __syncthreads();
    }

#pragma unroll
    for (int mi = 0; mi < 4; ++mi) {
        int obase = wm * 64 + mi * 16 + quad * 4;
        float bv[4];
#pragma unroll
        for (int r = 0; r < 4; ++r) bv[r] = bias[m0 + obase + r];
        float sr[4] = {0.f, 0.f, 0.f, 0.f}, qr[4] = {0.f, 0.f, 0.f, 0.f};
#pragma unroll
        for (int ni = 0; ni < 4; ++ni) {
            int j_local = wn * 64 + ni * 16 + l16;
            ushort4 pk;
            float v0 = acc[mi][ni][0] + bv[0];
            float v1 = acc[mi][ni][1] + bv[1];
            float v2 = acc[mi][ni][2] + bv[2];
            float v3 = acc[mi][ni][3] + bv[3];
            pk.x = f2b(v0); pk.y = f2b(v1); pk.z = f2b(v2); pk.w = f2b(v3);
            sr[0] += v0; qr[0] += v0 * v0;
            sr[1] += v1; qr[1] += v1 * v1;
            sr[2] += v2; qr[2] += v2 * v2;
            sr[3] += v3; qr[3] += v3 * v3;
            *(ushort4*)(sY + j_local * 136 + obase) = pk;
        }
#pragma unroll
        for (int r = 0; r < 4; ++r) {
            float s = sr[r], q = qr[r];
            s += __shfl_xor(s, 1); s += __shfl_xor(s, 2);
            s += __shfl_xor(s, 4); s += __shfl_xor(s, 8);
            q += __shfl_xor(q, 1); q += __shfl_xor(q, 2);
            q += __shfl_xor(q, 4); q += __shfl_xor(q, 8);
            if (l16 == 0) {
                atomicAdd(&red_s[obase + r], s);
                atomicAdd(&red_q[obase + r], q);
            }
        }
    }
    __syncthreads();

#pragma unroll
    for (int rep = 0; rep < 8; ++rep) {
        int idx = rep * 256 + t;
        int jl = idx >> 4;
        int o8 = idx & 15;
        uint4 vv = *(const uint4*)(sY + jl * 136 + o8 * 8);
        *(uint4*)(Y + (size_t)(j0 + jl) * Mtot + m0 + o8 * 8) = vv;
    }
    if (t < 128) {
        part_s[(size_t)blockIdx.y * Mtot + m0 + t] = red_s[t];
        part_q[(size_t)blockIdx.y * Mtot + m0 + t] = red_q[t];
    }
}

// ---------------------------------------------------------------------------
// Parallel BN finalize: one block per channel. Previously a SINGLE
// 256-thread block looped 512x over 1MB of partials (latency-bound on one
// CU, on the critical path twice). Fixed-order tree reduction: deterministic.
__global__ __launch_bounds__(256) void k_bnfin(const float* __restrict__ part_s,
                                               const float* __restrict__ part_q,
                                               int nby,
                                               const float* __restrict__ gamma,
                                               const float* __restrict__ beta,
                                               float* __restrict__ a, float* __restrict__ bb,
                                               int C, float inv_count) {
    __shared__ float rs[4], rq[4];
    int i = blockIdx.x;      // channel
    int t = threadIdx.x;
    float s = 0.f, q = 0.f;
    for (int by = t; by < nby; by += 256) {
        s += part_s[(size_t)by * C + i];
        q += part_q[(size_t)by * C + i];
    }
    s += __shfl_xor(s, 1);  q += __shfl_xor(q, 1);
    s += __shfl_xor(s, 2);  q += __shfl_xor(q, 2);
    s += __shfl_xor(s, 4);  q += __shfl_xor(q, 4);
    s += __shfl_xor(s, 8);  q += __shfl_xor(q, 8);
    s += __shfl_xor(s, 16); q += __shfl_xor(q, 16);
    s += __shfl_xor(s, 32); q += __shfl_xor(q, 32);
    int wv = t >> 6, ln = t & 63;
    if (ln == 0) { rs[wv] = s; rq[wv] = q; }
    __syncthreads();
    if (t == 0) {
        s = (rs[0] + rs[1]) + (rs[2] + rs[3]);
        q = (rq[0] + rq[1]) + (rq[2] + rq[3]);
        float mean = s * inv_count;
        float var = q * inv_count - mean * mean;
        float sc = gamma[i] / sqrtf(var + 1e-5f);
        a[i] = sc;
        bb[i] = beta[i] - mean * sc;
    }
}

// ---------------------------------------------------------------------------
__global__ __launch_bounds__(256) void k_out(const ushort_t* __restrict__ Y1,
                                             const float* __restrict__ a,
                                             const float* __restrict__ bb,
                                             float* __restrict__ out) {
    __shared__ float sa[128], sb[128];
    int t = threadIdx.x;
    if (t < 128) { sa[t] = a[t]; sb[t] = bb[t]; }
    __syncthreads();
    int b = blockIdx.x;
    int nl = t & 127;
    int half = t >> 7;
    int n = blockIdx.y * 128 + nl;
    const uint4* src = (const uint4*)(Y1 + (size_t)(b * 4096 + n) * 128);
    float* dst = out + (size_t)b * 128 * 4096 + n;
    uint4 raw[8];
#pragma unroll
    for (int p = 0; p < 8; ++p) raw[p] = src[half * 8 + p];
    const ushort_t* e = (const ushort_t*)raw;
#pragma unroll
    for (int c = 0; c < 64; ++c) {
        int ch = half * 64 + c;
        float v = b2f(e[c]);
        v = fmaxf(sa[ch] * v + sb[ch], 0.f);
        dst[(size_t)ch * 4096] = v;
    }
}

// ---------------------------------------------------------------------------
extern "C" void kernel_launch(void* const* d_in, const int* in_sizes, int n_in,
                              void* d_out, int out_size, void* d_ws, size_t ws_size,
                              hipStream_t stream) {
    const float* xyz1    = (const float*)d_in[0];
    const float* xyz2    = (const float*)d_in[1];
    const float* points1 = (const float*)d_in[2];
    const float* points2 = (const float*)d_in[3];
    const float* w0      = (const float*)d_in[4];
    const float* b0      = (const float*)d_in[5];
    const float* gamma0  = (const float*)d_in[6];
    const float* beta0   = (const float*)d_in[7];
    const float* w1      = (const float*)d_in[8];
    const float* b1      = (const float*)d_in[9];
    const float* gamma1  = (const float*)d_in[10];
    const float* beta1   = (const float*)d_in[11];
    float* out = (float*)d_out;

    char* ws = (char*)d_ws;
    const size_t OFF_X    = 0;                       // 67108864
    const size_t OFF_Y0   = 67108864;                // 33554432
    const size_t OFF_Y1   = 100663296;               // 16777216
    const size_t OFF_P2T  = 117440512;               // 4194304
    const size_t OFF_W0B  = 121634816;               // 262144
    const size_t OFF_W1B  = 121896960;               // 65536
    const size_t OFF_AB   = 121962496;               // 3072
    const size_t OFF_SDAT = 121965568;               // 262144
    const size_t OFF_PS0  = 122227712;               // 524288
    const size_t OFF_PQ0  = 122752000;               // 524288
    const size_t OFF_PS1  = 123276288;               // 262144
    const size_t OFF_PQ1  = 123538432;               // 262144

    ushort_t* X    = (ushort_t*)(ws + OFF_X);
    ushort_t* Y0   = (ushort_t*)(ws + OFF_Y0);
    ushort_t* Y1   = (ushort_t*)(ws + OFF_Y1);
    ushort_t* p2t  = (ushort_t*)(ws + OFF_P2T);
    ushort_t* w0b  = (ushort_t*)(ws + OFF_W0B);
    ushort_t* w1b  = (ushort_t*)(ws + OFF_W1B);
    float* ab      = (float*)(ws + OFF_AB);
    float4* sdat   = (float4*)(ws + OFF_SDAT);
    float* ps0 = (float*)(ws + OFF_PS0);
    float* pq0 = (float*)(ws + OFF_PQ0);
    float* ps1 = (float*)(ws + OFF_PS1);
    float* pq1 = (float*)(ws + OFF_PQ1);
    float* a0 = ab;       float* bb0 = ab + 256;
    float* a1 = ab + 512; float* bb1 = ab + 640;

    k_pre<<<960, 256, 0, stream>>>(w0, w0b, w1, w1b, xyz2, sdat, points2, p2t);
    k_interp<<<dim3(16, 128), 256, 0, stream>>>(xyz1, sdat, points1, p2t, X);
    k_gemm<<<dim3(2, 512), 256, 0, stream>>>(w0b, X, b0, Y0, ps0, pq0, 256, 512);
    k_bnfin<<<256, 256, 0, stream>>>(ps0, pq0, 512, gamma0, beta0, a0, bb0, 256, 1.0f / 65536.0f);
    k_gemmf<<<dim3(1, 512), 256, 0, stream>>>(w1b, Y0, b1, a0, bb0, Y1, ps1, pq1, 128, 256);
    k_bnfin<<<128, 256, 0, stream>>>(ps1, pq1, 512, gamma1, beta1, a1, bb1, 128, 1.0f / 65536.0f);
    k_out<<<dim3(16, 32), 256, 0, stream>>>(Y1, a1, bb1, out);
}

// Round 4
// 218.609 us; speedup vs baseline: 1.2783x; 1.0102x over previous
//
#include <hip/hip_runtime.h>
#include <stdint.h>

typedef unsigned short ushort_t;
typedef __attribute__((ext_vector_type(8))) __bf16 bf16x8;
typedef __attribute__((ext_vector_type(4))) float f32x4;

__device__ __forceinline__ float b2f(ushort_t u) {
    unsigned v = ((unsigned)u) << 16;
    float f;
    __builtin_memcpy(&f, &v, 4);
    return f;
}

// RNE f32->bf16 via compiler cast (v_cvt path on gfx950; identical RNE
// rounding to the old integer sequence, ~4 ops cheaper).
__device__ __forceinline__ ushort_t f2b(float f) {
    __bf16 h = (__bf16)f;
    return __builtin_bit_cast(ushort_t, h);
}

__device__ __forceinline__ void gl_lds16(const void* g, void* l) {
    __builtin_amdgcn_global_load_lds((const __attribute__((address_space(1))) void*)g,
                                     (__attribute__((address_space(3))) void*)l, 16, 0, 0);
}

// ---------------------------------------------------------------------------
// Fused preprocessing: w0/w1 bf16-cvt, sdat build, points2 transpose.
__global__ __launch_bounds__(256) void k_pre(const float* __restrict__ w0, ushort_t* __restrict__ w0b,
                                             const float* __restrict__ w1, ushort_t* __restrict__ w1b,
                                             const float* __restrict__ xyz2, float4* __restrict__ sdat,
                                             const float* __restrict__ points2, ushort_t* __restrict__ p2t) {
    int bid = blockIdx.x;
    int t = threadIdx.x;
    if (bid < 512) {
        int i = bid * 256 + t;
        w0b[i] = f2b(w0[i]);
    } else if (bid < 640) {
        int i = (bid - 512) * 256 + t;
        w1b[i] = f2b(w1[i]);
    } else if (bid < 704) {
        int bb = bid - 640;
        int b = bb & 15, by = bb >> 4;
        int s = by * 256 + t;
        const float* x2 = xyz2 + (size_t)b * 3 * 1024;
        float x = x2[s], y = x2[1024 + s], z = x2[2048 + s];
        float4 v;
        v.x = x; v.y = y; v.z = z;
        v.w = __fadd_rn(__fadd_rn(__fmul_rn(x, x), __fmul_rn(y, y)), __fmul_rn(z, z));
        sdat[(size_t)b * 1024 + s] = v;
    } else {
        int bb = bid - 704;
        int b = bb & 15, sy = bb >> 4;
        int s = sy * 64 + (t & 63);
        int g = t >> 6;
        const float* src = points2 + (size_t)b * 128 * 1024 + s;
        ushort_t* dst = p2t + ((size_t)b * 1024 + s) * 128;
#pragma unroll
        for (int i = 0; i < 4; ++i) {
            int cp = i * 4 + g;
            ushort_t tmp[8];
#pragma unroll
            for (int k = 0; k < 8; ++k) tmp[k] = f2b(src[(size_t)(cp * 8 + k) * 1024]);
            *(uint4*)(dst + cp * 8) = *(const uint4*)tmp;
        }
    }
}

// ---------------------------------------------------------------------------
// 3-NN + build X [65536][512] bf16. 32 queries/block, 8 slices x 128 points.
// sdat[b] staged to LDS once per block (load-bearing: removing it made the
// scan L2-latency-bound). points1 loads hoisted ABOVE the scan loop: the
// scan has no VMEM ops, so these 16 HBM loads complete under ~4400 cycles
// of scan VALU work instead of stalling serially afterward.
__global__ __launch_bounds__(256) void k_interp(const float* __restrict__ xyz1,
                                                const float4* __restrict__ sdat,
                                                const float* __restrict__ points1,
                                                const ushort_t* __restrict__ p2t,
                                                ushort_t* __restrict__ X) {
    int b = blockIdx.x;
    int n0 = blockIdx.y * 32;
    int t = threadIdx.x;
    int tq = t & 31;        // query within block
    int slice = t >> 5;     // 0..7
    int wave = t >> 6, lane = t & 63;

    __shared__ __align__(16) char sbuf[16384];  // sP during scan; sidx/sw after
    float4* sP = (float4*)sbuf;                 // 1024 float4 staged sdat[b]
    int*   sidx = (int*)sbuf;                   // 32*3 ints   (after scan)
    float* sw   = (float*)(sbuf + 384);         // 32*3 floats (after scan)
    __shared__ float sD[256 * 3];
    __shared__ int   sI[256 * 3];

    // stage sdat[b] -> LDS (wave w loads points [w*256, w*256+256))
    {
        const float4* src = sdat + (size_t)b * 1024;
#pragma unroll
        for (int c = 0; c < 4; ++c) {
            int p = wave * 256 + c * 64 + lane;
            gl_lds16(src + p, sbuf + p * 16);
        }
    }

    int n = n0 + tq;
    float x = xyz1[((size_t)b * 3 + 0) * 4096 + n];
    float y = xyz1[((size_t)b * 3 + 1) * 4096 + n];
    float z = xyz1[((size_t)b * 3 + 2) * 4096 + n];
    float s1 = __fadd_rn(__fadd_rn(__fmul_rn(x, x), __fmul_rn(y, y)), __fmul_rn(z, z));

    __syncthreads();   // staging complete (drains all vmcnt incl. gl_lds)

    // Issue points1 loads now: they ride out the scan in the vmem queue.
    const float* p1base = points1 + (size_t)b * 128 * 4096 + n0 + tq;
    float p1v[16];
#pragma unroll
    for (int i = 0; i < 2; ++i)
#pragma unroll
        for (int k = 0; k < 8; ++k)
            p1v[i * 8 + k] = p1base[(size_t)(((i * 8 + slice) * 8) + k) * 4096];

    float d0 = 1e30f, d1 = 1e30f, d2 = 1e30f;
    int i0 = 0, i1 = 0, i2 = 0;
    int sbeg = slice * 128;
    const float4* sdL = sP + sbeg;
#pragma unroll 8
    for (int s = 0; s < 128; ++s) {
        float4 v = sdL[s];
        float dot = fmaf(z, v.z, fmaf(y, v.y, __fmul_rn(x, v.x)));
        // fmaf(-2,dot,s1) == add(mul(-2,dot),s1) bit-exactly: *2 is exact.
        float d = __fadd_rn(fmaf(-2.0f, dot, s1), v.w);
        int si = sbeg + s;
        bool c0 = d < d0, c1 = d < d1, c2 = d < d2;
        // indices: identical logic to the verified version
        i2 = c1 ? i1 : (c2 ? si : i2);
        i1 = c0 ? i0 : (c1 ? si : i1);
        i0 = c0 ? si : i0;
        // distances: min/max forms select bit-identical values
        d2 = fminf(fmaxf(d, d1), d2);
        d1 = fminf(fmaxf(d, d0), d1);
        d0 = fminf(d, d0);
    }
    sD[t * 3 + 0] = d0; sD[t * 3 + 1] = d1; sD[t * 3 + 2] = d2;
    sI[t * 3 + 0] = i0; sI[t * 3 + 1] = i1; sI[t * 3 + 2] = i2;

    // points1 part: X[j][0:128] = bf16(points1[b][:, n]) (loads done above)
    {
        ushort_t* dstbase = X + (size_t)(b * 4096 + n0 + tq) * 512;
#pragma unroll
        for (int i = 0; i < 2; ++i) {
            int piece = i * 8 + slice;
            ushort_t tmp[8];
#pragma unroll
            for (int k = 0; k < 8; ++k) tmp[k] = f2b(p1v[i * 8 + k]);
            *(uint4*)(dstbase + piece * 8) = *(const uint4*)tmp;
        }
    }
    __syncthreads();   // scan + sD/sI complete; sP now dead

    // merge: threads t<32 pick global top-3 of 24 candidates by lex (d, idx).
    if (t < 32) {
        int sel0 = -1, sel1 = -1;
        float seld[3]; int seli[3];
#pragma unroll
        for (int r = 0; r < 3; ++r) {
            float bd = 1e38f; int bi = 1 << 30;
            for (int k = 0; k < 24; ++k) {
                int s3 = (k * 0xAAAB) >> 17;    // k/3 for k<=23
                int rank = k - s3 * 3;
                int base = (s3 * 32 + t) * 3 + rank;
                float cd = sD[base];
                int ci = sI[base];
                bool excl = (ci == sel0) | (ci == sel1);
                bool better = (!excl) & ((cd < bd) | ((cd == bd) & (ci < bi)));
                if (better) { bd = cd; bi = ci; }
            }
            seld[r] = bd; seli[r] = bi;
            if (r == 0) sel0 = bi; else if (r == 1) sel1 = bi;
        }
        float r0 = 1.0f / (seld[0] + 1e-8f);
        float r1 = 1.0f / (seld[1] + 1e-8f);
        float r2 = 1.0f / (seld[2] + 1e-8f);
        float rs = r0 + r1 + r2;
        sw[t * 3 + 0] = r0 / rs; sw[t * 3 + 1] = r1 / rs; sw[t * 3 + 2] = r2 / rs;
        sidx[t * 3 + 0] = seli[0]; sidx[t * 3 + 1] = seli[1]; sidx[t * 3 + 2] = seli[2];
    }
    __syncthreads();

    // gather: 32 queries x 48 pieces = 1536 items
#pragma unroll
    for (int i = 0; i < 6; ++i) {
        int idx = i * 256 + t;
        int q = idx / 48;
        int rem = idx - q * 48;
        int r = rem >> 4;
        int piece = rem & 15;
        int si = sidx[q * 3 + r];
        float wt = sw[q * 3 + r];
        const ushort_t* src = p2t + ((size_t)b * 1024 + si) * 128 + piece * 8;
        uint4 raw = *(const uint4*)src;
        ushort_t* e = (ushort_t*)&raw;
        ushort_t outv[8];
#pragma unroll
        for (int k = 0; k < 8; ++k) outv[k] = f2b(wt * b2f(e[k]));
        ushort_t* dst = X + (size_t)(b * 4096 + n0 + q) * 512 + 128 + r * 128 + piece * 8;
        *(uint4*)dst = *(const uint4*)outv;
    }
}

// ---------------------------------------------------------------------------
// GEMM0: Y[j][o] = sum_k A[o][k]*Bt[j][k] + bias[o]
// BK=64: halves the vmcnt(0)+barrier drain count (the dominant per-step
// cost at these tiny K-loops); 32 MFMA per barrier. K-block accumulation
// sequence identical to BK=32 -> bit-identical results.
__global__ __launch_bounds__(256) void k_gemm(const ushort_t* __restrict__ A,
                                              const ushort_t* __restrict__ Bt,
                                              const float* __restrict__ bias,
                                              ushort_t* __restrict__ Y,
                                              float* __restrict__ part_s,
                                              float* __restrict__ part_q,
                                              int Mtot, int K) {
    __shared__ __align__(16) char smem[35840];
    ushort_t* As = (ushort_t*)smem;               // 128 x 64 bf16 = 16 KB
    ushort_t* Bs = (ushort_t*)(smem + 16384);     // 128 x 64 bf16 = 16 KB
    ushort_t* sY = (ushort_t*)smem;               // epilogue reuse (34816 B)
    float* red_s = (float*)(smem + 34816);
    float* red_q = red_s + 128;

    int t = threadIdx.x;
    int m0 = blockIdx.x * 128;
    int j0 = blockIdx.y * 128;
    int wave = t >> 6, lane = t & 63;
    int wm = wave >> 1, wn = wave & 1;
    int l16 = lane & 15, quad = lane >> 4;

    if (t < 128) { red_s[t] = 0.f; red_q[t] = 0.f; }

    f32x4 acc[4][4] = {};

    int nk = K >> 6;
    for (int kt = 0; kt < nk; ++kt) {
#pragma unroll
        for (int c = 0; c < 4; ++c) {
            int idx = c * 256 + t;
            int row = idx >> 3, kc = idx & 7;
            gl_lds16(A + (size_t)(m0 + row) * K + kt * 64 + kc * 8, As + idx * 8);
            gl_lds16(Bt + (size_t)(j0 + row) * K + kt * 64 + kc * 8, Bs + idx * 8);
        }
        __syncthreads();

#pragma unroll
        for (int kk = 0; kk < 2; ++kk) {
            bf16x8 af[4], bfr[4];
#pragma unroll
            for (int mi = 0; mi < 4; ++mi)
                af[mi] = *(const bf16x8*)(As + (wm * 64 + mi * 16 + l16) * 64 + kk * 32 + quad * 8);
#pragma unroll
            for (int ni = 0; ni < 4; ++ni)
                bfr[ni] = *(const bf16x8*)(Bs + (wn * 64 + ni * 16 + l16) * 64 + kk * 32 + quad * 8);
#pragma unroll
            for (int mi = 0; mi < 4; ++mi)
#pragma unroll
                for (int ni = 0; ni < 4; ++ni)
                    acc[mi][ni] = __builtin_amdgcn_mfma_f32_16x16x32_bf16(af[mi], bfr[ni], acc[mi][ni], 0, 0, 0);
        }
        __syncthreads();
    }

#pragma unroll
    for (int mi = 0; mi < 4; ++mi) {
        int obase = wm * 64 + mi * 16 + quad * 4;
        float bv[4];
#pragma unroll
        for (int r = 0; r < 4; ++r) bv[r] = bias[m0 + obase + r];
        float sr[4] = {0.f, 0.f, 0.f, 0.f}, qr[4] = {0.f, 0.f, 0.f, 0.f};
#pragma unroll
        for (int ni = 0; ni < 4; ++ni) {
            int j_local = wn * 64 + ni * 16 + l16;
            ushort4 pk;
            float v0 = acc[mi][ni][0] + bv[0];
            float v1 = acc[mi][ni][1] + bv[1];
            float v2 = acc[mi][ni][2] + bv[2];
            float v3 = acc[mi][ni][3] + bv[3];
            pk.x = f2b(v0); pk.y = f2b(v1); pk.z = f2b(v2); pk.w = f2b(v3);
            sr[0] += v0; qr[0] += v0 * v0;
            sr[1] += v1; qr[1] += v1 * v1;
            sr[2] += v2; qr[2] += v2 * v2;
            sr[3] += v3; qr[3] += v3 * v3;
            *(ushort4*)(sY + j_local * 136 + obase) = pk;
        }
#pragma unroll
        for (int r = 0; r < 4; ++r) {
            float s = sr[r], q = qr[r];
            s += __shfl_xor(s, 1); s += __shfl_xor(s, 2);
            s += __shfl_xor(s, 4); s += __shfl_xor(s, 8);
            q += __shfl_xor(q, 1); q += __shfl_xor(q, 2);
            q += __shfl_xor(q, 4); q += __shfl_xor(q, 8);
            if (l16 == 0) {
                atomicAdd(&red_s[obase + r], s);
                atomicAdd(&red_q[obase + r], q);
            }
        }
    }
    __syncthreads();

#pragma unroll
    for (int rep = 0; rep < 8; ++rep) {
        int idx = rep * 256 + t;
        int jl = idx >> 4;
        int o8 = idx & 15;
        uint4 vv = *(const uint4*)(sY + jl * 136 + o8 * 8);
        *(uint4*)(Y + (size_t)(j0 + jl) * Mtot + m0 + o8 * 8) = vv;
    }
    if (t < 128) {
        part_s[(size_t)blockIdx.y * Mtot + m0 + t] = red_s[t];
        part_q[(size_t)blockIdx.y * Mtot + m0 + t] = red_q[t];
    }
}

// ---------------------------------------------------------------------------
// GEMM1 with fused BN0+ReLU applied to the B (Y0) tiles at staging time.
// BK=64 (4 K-steps). sa/sb moved to 32768..34816 (dead before sY epilogue
// overwrites that range); red_s/q at 34816 untouched by staging or sY.
__global__ __launch_bounds__(256) void k_gemmf(const ushort_t* __restrict__ A,
                                               const ushort_t* __restrict__ Y0,
                                               const float* __restrict__ bias,
                                               const float* __restrict__ act_a,
                                               const float* __restrict__ act_b,
                                               ushort_t* __restrict__ Y,
                                               float* __restrict__ part_s,
                                               float* __restrict__ part_q,
                                               int Mtot, int K) {
    __shared__ __align__(16) char smem[35840];
    ushort_t* As = (ushort_t*)smem;               // 128 x 64 = 16 KB
    ushort_t* Bs = (ushort_t*)(smem + 16384);     // 128 x 64 = 16 KB
    float* sa = (float*)(smem + 32768);           // 256 floats
    float* sb = (float*)(smem + 33792);           // 256 floats
    ushort_t* sY = (ushort_t*)smem;               // epilogue reuse
    float* red_s = (float*)(smem + 34816);
    float* red_q = red_s + 128;

    int t = threadIdx.x;
    int m0 = blockIdx.x * 128;
    int j0 = blockIdx.y * 128;
    int wave = t >> 6, lane = t & 63;
    int wm = wave >> 1, wn = wave & 1;
    int l16 = lane & 15, quad = lane >> 4;

    sa[t] = act_a[t]; sb[t] = act_b[t];
    if (t < 128) { red_s[t] = 0.f; red_q[t] = 0.f; }
    __syncthreads();

    f32x4 acc[4][4] = {};

    int nk = K >> 6;
    for (int kt = 0; kt < nk; ++kt) {
#pragma unroll
        for (int c = 0; c < 4; ++c) {
            int idx = c * 256 + t;
            int row = idx >> 3, kc = idx & 7;
            gl_lds16(A + (size_t)(m0 + row) * K + kt * 64 + kc * 8, As + idx * 8);
        }
#pragma unroll
        for (int c = 0; c < 4; ++c) {
            int idx = c * 256 + t;
            int row = idx >> 3, kc = idx & 7;
            int cbase = kt * 64 + kc * 8;
            uint4 raw = *(const uint4*)(Y0 + (size_t)(j0 + row) * K + cbase);
            ushort_t* e = (ushort_t*)&raw;
            ushort_t outv[8];
#pragma unroll
            for (int k = 0; k < 8; ++k) {
                float v = fmaxf(sa[cbase + k] * b2f(e[k]) + sb[cbase + k], 0.f);
                outv[k] = f2b(v);
            }
            *(uint4*)(Bs + idx * 8) = *(const uint4*)outv;
        }
        __syncthreads();

#pragma unroll
        for (int kk = 0; kk < 2; ++kk) {
            bf16x8 af[4], bfr[4];
#pragma unroll
            for (int mi = 0; mi < 4; ++mi)
                af[mi] = *(const bf16x8*)(As + (wm * 64 + mi * 16 + l16) * 64 + kk * 32 + quad * 8);
#pragma unroll
            for (int ni = 0; ni < 4; ++ni)
                bfr[ni] = *(const bf16x8*)(Bs + (wn * 64 + ni * 16 + l16) * 64 + kk * 32 + quad * 8);
#pragma unroll
            for (int mi = 0; mi < 4; ++mi)
#pragma unroll
                for (int ni = 0; ni < 4; ++ni)
                    acc[mi][ni] = __builtin_amdgcn_mfma_f32_16x16x32_bf16(af[mi], bfr[ni], acc[mi][ni], 0, 0, 0);
        }
        __syncthreads();
    }

#pragma unroll
    for (int mi = 0; mi < 4; ++mi) {
        int obase = wm * 64 + mi * 16 + quad * 4;
        float bv[4];
#pragma unroll
        for (int r = 0; r < 4; ++r) bv[r] = bias[m0 + obase + r];
        float sr[4] = {0.f, 0.f, 0.f, 0.f}, qr[4] = {0.f, 0.f, 0.f, 0.f};
#pragma unroll
        for (int ni = 0; ni < 4; ++ni) {
            int j_local = wn * 64 + ni * 16 + l16;
            ushort4 pk;
            float v0 = acc[mi][ni][0] + bv[0];
            float v1 = acc[mi][ni][1] + bv[1];
            float v2 = acc[mi][ni][2] + bv[2];
            float v3 = acc[mi][ni][3] + bv[3];
            pk.x = f2b(v0); pk.y = f2b(v1); pk.z = f2b(v2); pk.w = f2b(v3);
            sr[0] += v0; qr[0] += v0 * v0;
            sr[1] += v1; qr[1] += v1 * v1;
            sr[2] += v2; qr[2] += v2 * v2;
            sr[3] += v3; qr[3] += v3 * v3;
            *(ushort4*)(sY + j_local * 136 + obase) = pk;
        }
#pragma unroll
        for (int r = 0; r < 4; ++r) {
            float s = sr[r], q = qr[r];
            s += __shfl_xor(s, 1); s += __shfl_xor(s, 2);
            s += __shfl_xor(s, 4); s += __shfl_xor(s, 8);
            q += __shfl_xor(q, 1); q += __shfl_xor(q, 2);
            q += __shfl_xor(q, 4); q += __shfl_xor(q, 8);
            if (l16 == 0) {
                atomicAdd(&red_s[obase + r], s);
                atomicAdd(&red_q[obase + r], q);
            }
        }
    }
    __syncthreads();

#pragma unroll
    for (int rep = 0; rep < 8; ++rep) {
        int idx = rep * 256 + t;
        int jl = idx >> 4;
        int o8 = idx & 15;
        uint4 vv = *(const uint4*)(sY + jl * 136 + o8 * 8);
        *(uint4*)(Y + (size_t)(j0 + jl) * Mtot + m0 + o8 * 8) = vv;
    }
    if (t < 128) {
        part_s[(size_t)blockIdx.y * Mtot + m0 + t] = red_s[t];
        part_q[(size_t)blockIdx.y * Mtot + m0 + t] = red_q[t];
    }
}

// ---------------------------------------------------------------------------
// Parallel BN finalize: one block per channel (was a single serial block,
// ~22 us each on the critical path). Fixed-order tree: deterministic.
__global__ __launch_bounds__(256) void k_bnfin(const float* __restrict__ part_s,
                                               const float* __restrict__ part_q,
                                               int nby,
                                               const float* __restrict__ gamma,
                                               const float* __restrict__ beta,
                                               float* __restrict__ a, float* __restrict__ bb,
                                               int C, float inv_count) {
    __shared__ float rs[4], rq[4];
    int i = blockIdx.x;      // channel
    int t = threadIdx.x;
    float s = 0.f, q = 0.f;
    for (int by = t; by < nby; by += 256) {
        s += part_s[(size_t)by * C + i];
        q += part_q[(size_t)by * C + i];
    }
    s += __shfl_xor(s, 1);  q += __shfl_xor(q, 1);
    s += __shfl_xor(s, 2);  q += __shfl_xor(q, 2);
    s += __shfl_xor(s, 4);  q += __shfl_xor(q, 4);
    s += __shfl_xor(s, 8);  q += __shfl_xor(q, 8);
    s += __shfl_xor(s, 16); q += __shfl_xor(q, 16);
    s += __shfl_xor(s, 32); q += __shfl_xor(q, 32);
    int wv = t >> 6, ln = t & 63;
    if (ln == 0) { rs[wv] = s; rq[wv] = q; }
    __syncthreads();
    if (t == 0) {
        s = (rs[0] + rs[1]) + (rs[2] + rs[3]);
        q = (rq[0] + rq[1]) + (rq[2] + rq[3]);
        float mean = s * inv_count;
        float var = q * inv_count - mean * mean;
        float sc = gamma[i] / sqrtf(var + 1e-5f);
        a[i] = sc;
        bb[i] = beta[i] - mean * sc;
    }
}

// ---------------------------------------------------------------------------
__global__ __launch_bounds__(256) void k_out(const ushort_t* __restrict__ Y1,
                                             const float* __restrict__ a,
                                             const float* __restrict__ bb,
                                             float* __restrict__ out) {
    __shared__ float sa[128], sb[128];
    int t = threadIdx.x;
    if (t < 128) { sa[t] = a[t]; sb[t] = bb[t]; }
    __syncthreads();
    int b = blockIdx.x;
    int nl = t & 127;
    int half = t >> 7;
    int n = blockIdx.y * 128 + nl;
    const uint4* src = (const uint4*)(Y1 + (size_t)(b * 4096 + n) * 128);
    float* dst = out + (size_t)b * 128 * 4096 + n;
    uint4 raw[8];
#pragma unroll
    for (int p = 0; p < 8; ++p) raw[p] = src[half * 8 + p];
    const ushort_t* e = (const ushort_t*)raw;
#pragma unroll
    for (int c = 0; c < 64; ++c) {
        int ch = half * 64 + c;
        float v = b2f(e[c]);
        v = fmaxf(sa[ch] * v + sb[ch], 0.f);
        dst[(size_t)ch * 4096] = v;
    }
}

// ---------------------------------------------------------------------------
extern "C" void kernel_launch(void* const* d_in, const int* in_sizes, int n_in,
                              void* d_out, int out_size, void* d_ws, size_t ws_size,
                              hipStream_t stream) {
    const float* xyz1    = (const float*)d_in[0];
    const float* xyz2    = (const float*)d_in[1];
    const float* points1 = (const float*)d_in[2];
    const float* points2 = (const float*)d_in[3];
    const float* w0      = (const float*)d_in[4];
    const float* b0      = (const float*)d_in[5];
    const float* gamma0  = (const float*)d_in[6];
    const float* beta0   = (const float*)d_in[7];
    const float* w1      = (const float*)d_in[8];
    const float* b1      = (const float*)d_in[9];
    const float* gamma1  = (const float*)d_in[10];
    const float* beta1   = (const float*)d_in[11];
    float* out = (float*)d_out;

    char* ws = (char*)d_ws;
    const size_t OFF_X    = 0;                       // 67108864
    const size_t OFF_Y0   = 67108864;                // 33554432
    const size_t OFF_Y1   = 100663296;               // 16777216
    const size_t OFF_P2T  = 117440512;               // 4194304
    const size_t OFF_W0B  = 121634816;               // 262144
    const size_t OFF_W1B  = 121896960;               // 65536
    const size_t OFF_AB   = 121962496;               // 3072
    const size_t OFF_SDAT = 121965568;               // 262144
    const size_t OFF_PS0  = 122227712;               // 524288
    const size_t OFF_PQ0  = 122752000;               // 524288
    const size_t OFF_PS1  = 123276288;               // 262144
    const size_t OFF_PQ1  = 123538432;               // 262144

    ushort_t* X    = (ushort_t*)(ws + OFF_X);
    ushort_t* Y0   = (ushort_t*)(ws + OFF_Y0);
    ushort_t* Y1   = (ushort_t*)(ws + OFF_Y1);
    ushort_t* p2t  = (ushort_t*)(ws + OFF_P2T);
    ushort_t* w0b  = (ushort_t*)(ws + OFF_W0B);
    ushort_t* w1b  = (ushort_t*)(ws + OFF_W1B);
    float* ab      = (float*)(ws + OFF_AB);
    float4* sdat   = (float4*)(ws + OFF_SDAT);
    float* ps0 = (float*)(ws + OFF_PS0);
    float* pq0 = (float*)(ws + OFF_PQ0);
    float* ps1 = (float*)(ws + OFF_PS1);
    float* pq1 = (float*)(ws + OFF_PQ1);
    float* a0 = ab;       float* bb0 = ab + 256;
    float* a1 = ab + 512; float* bb1 = ab + 640;

    k_pre<<<960, 256, 0, stream>>>(w0, w0b, w1, w1b, xyz2, sdat, points2, p2t);
    k_interp<<<dim3(16, 128), 256, 0, stream>>>(xyz1, sdat, points1, p2t, X);
    k_gemm<<<dim3(2, 512), 256, 0, stream>>>(w0b, X, b0, Y0, ps0, pq0, 256, 512);
    k_bnfin<<<256, 256, 0, stream>>>(ps0, pq0, 512, gamma0, beta0, a0, bb0, 256, 1.0f / 65536.0f);
    k_gemmf<<<dim3(1, 512), 256, 0, stream>>>(w1b, Y0, b1, a0, bb0, Y1, ps1, pq1, 128, 256);
    k_bnfin<<<128, 256, 0, stream>>>(ps1, pq1, 512, gamma1, beta1, a1, bb1, 128, 1.0f / 65536.0f);
    k_out<<<dim3(16, 32), 256, 0, stream>>>(Y1, a1, bb1, out);
}

// Round 5
// 212.700 us; speedup vs baseline: 1.3138x; 1.0278x over previous
//
#include <hip/hip_runtime.h>
#include <stdint.h>

typedef unsigned short ushort_t;
typedef __attribute__((ext_vector_type(8))) __bf16 bf16x8;
typedef __attribute__((ext_vector_type(4))) float f32x4;

__device__ __forceinline__ float b2f(ushort_t u) {
    unsigned v = ((unsigned)u) << 16;
    float f;
    __builtin_memcpy(&f, &v, 4);
    return f;
}

// RNE f32->bf16 via compiler cast (v_cvt path on gfx950; identical RNE
// rounding to the old integer sequence, ~4 ops cheaper).
__device__ __forceinline__ ushort_t f2b(float f) {
    __bf16 h = (__bf16)f;
    return __builtin_bit_cast(ushort_t, h);
}

__device__ __forceinline__ void gl_lds16(const void* g, void* l) {
    __builtin_amdgcn_global_load_lds((const __attribute__((address_space(1))) void*)g,
                                     (__attribute__((address_space(3))) void*)l, 16, 0, 0);
}

// ---------------------------------------------------------------------------
// Fused preprocessing: w0/w1 bf16-cvt, sdat build, points2 transpose.
__global__ __launch_bounds__(256) void k_pre(const float* __restrict__ w0, ushort_t* __restrict__ w0b,
                                             const float* __restrict__ w1, ushort_t* __restrict__ w1b,
                                             const float* __restrict__ xyz2, float4* __restrict__ sdat,
                                             const float* __restrict__ points2, ushort_t* __restrict__ p2t) {
    int bid = blockIdx.x;
    int t = threadIdx.x;
    if (bid < 512) {
        int i = bid * 256 + t;
        w0b[i] = f2b(w0[i]);
    } else if (bid < 640) {
        int i = (bid - 512) * 256 + t;
        w1b[i] = f2b(w1[i]);
    } else if (bid < 704) {
        int bb = bid - 640;
        int b = bb & 15, by = bb >> 4;
        int s = by * 256 + t;
        const float* x2 = xyz2 + (size_t)b * 3 * 1024;
        float x = x2[s], y = x2[1024 + s], z = x2[2048 + s];
        float4 v;
        v.x = x; v.y = y; v.z = z;
        v.w = __fadd_rn(__fadd_rn(__fmul_rn(x, x), __fmul_rn(y, y)), __fmul_rn(z, z));
        sdat[(size_t)b * 1024 + s] = v;
    } else {
        int bb = bid - 704;
        int b = bb & 15, sy = bb >> 4;
        int s = sy * 64 + (t & 63);
        int g = t >> 6;
        const float* src = points2 + (size_t)b * 128 * 1024 + s;
        ushort_t* dst = p2t + ((size_t)b * 1024 + s) * 128;
#pragma unroll
        for (int i = 0; i < 4; ++i) {
            int cp = i * 4 + g;
            ushort_t tmp[8];
#pragma unroll
            for (int k = 0; k < 8; ++k) tmp[k] = f2b(src[(size_t)(cp * 8 + k) * 1024]);
            *(uint4*)(dst + cp * 8) = *(const uint4*)tmp;
        }
    }
}

// ---------------------------------------------------------------------------
// 3-NN + build X [65536][512] bf16. 64 queries/block (2 per thread sharing
// each staged-LDS point read), 8 slices x 128 points. grid 16x64 = 1024
// blocks = exactly 4 blocks/CU -> uniform single round, no tail; sP staging
// traffic halved. Per-query distance/selection math BIT-IDENTICAL to the
// verified version; merge candidate order identical.
__global__ __launch_bounds__(256, 4) void k_interp(const float* __restrict__ xyz1,
                                                   const float4* __restrict__ sdat,
                                                   const float* __restrict__ points1,
                                                   const ushort_t* __restrict__ p2t,
                                                   ushort_t* __restrict__ X) {
    int b = blockIdx.x;
    int n0 = blockIdx.y * 64;
    int t = threadIdx.x;
    int tq = t & 31;        // query A within block; query B = tq+32
    int slice = t >> 5;     // 0..7
    int wave = t >> 6, lane = t & 63;

    __shared__ __align__(16) char sbuf[16384];  // sP during scan; sidx/sw after
    float4* sP = (float4*)sbuf;                 // 1024 float4 staged sdat[b]
    int*   sidx = (int*)sbuf;                   // 64*3 ints   (after scan)
    float* sw   = (float*)(sbuf + 768);         // 64*3 floats (after scan)
    __shared__ float sD[1536];                  // (slice*64 + q)*3 + r
    __shared__ int   sI[1536];

    // stage sdat[b] -> LDS (wave w loads points [w*256, w*256+256))
    {
        const float4* src = sdat + (size_t)b * 1024;
#pragma unroll
        for (int c = 0; c < 4; ++c) {
            int p = wave * 256 + c * 64 + lane;
            gl_lds16(src + p, sbuf + p * 16);
        }
    }

    int nA = n0 + tq;
    float xA = xyz1[((size_t)b * 3 + 0) * 4096 + nA];
    float yA = xyz1[((size_t)b * 3 + 1) * 4096 + nA];
    float zA = xyz1[((size_t)b * 3 + 2) * 4096 + nA];
    float s1A = __fadd_rn(__fadd_rn(__fmul_rn(xA, xA), __fmul_rn(yA, yA)), __fmul_rn(zA, zA));
    float xB = xyz1[((size_t)b * 3 + 0) * 4096 + nA + 32];
    float yB = xyz1[((size_t)b * 3 + 1) * 4096 + nA + 32];
    float zB = xyz1[((size_t)b * 3 + 2) * 4096 + nA + 32];
    float s1B = __fadd_rn(__fadd_rn(__fmul_rn(xB, xB), __fmul_rn(yB, yB)), __fmul_rn(zB, zB));

    __syncthreads();   // staging complete (drains all vmcnt incl. gl_lds)

    // Issue points1 loads for BOTH queries now: they ride out the scan.
    const float* p1base = points1 + (size_t)b * 128 * 4096 + n0 + tq;
    float p1v[32];
#pragma unroll
    for (int i = 0; i < 2; ++i)
#pragma unroll
        for (int k = 0; k < 8; ++k) {
            size_t off = (size_t)(((i * 8 + slice) * 8) + k) * 4096;
            p1v[i * 8 + k]      = p1base[off];
            p1v[16 + i * 8 + k] = p1base[off + 32];
        }

    float d0A = 1e30f, d1A = 1e30f, d2A = 1e30f;
    int i0A = 0, i1A = 0, i2A = 0;
    float d0B = 1e30f, d1B = 1e30f, d2B = 1e30f;
    int i0B = 0, i1B = 0, i2B = 0;
    int sbeg = slice * 128;
    const float4* sdL = sP + sbeg;
#pragma unroll 4
    for (int s = 0; s < 128; ++s) {
        float4 v = sdL[s];
        int si = sbeg + s;
        // query A (math identical to verified version)
        {
            float dot = fmaf(zA, v.z, fmaf(yA, v.y, __fmul_rn(xA, v.x)));
            float d = __fadd_rn(fmaf(-2.0f, dot, s1A), v.w);
            bool c0 = d < d0A, c1 = d < d1A, c2 = d < d2A;
            i2A = c1 ? i1A : (c2 ? si : i2A);
            i1A = c0 ? i0A : (c1 ? si : i1A);
            i0A = c0 ? si : i0A;
            d2A = fminf(fmaxf(d, d1A), d2A);
            d1A = fminf(fmaxf(d, d0A), d1A);
            d0A = fminf(d, d0A);
        }
        // query B
        {
            float dot = fmaf(zB, v.z, fmaf(yB, v.y, __fmul_rn(xB, v.x)));
            float d = __fadd_rn(fmaf(-2.0f, dot, s1B), v.w);
            bool c0 = d < d0B, c1 = d < d1B, c2 = d < d2B;
            i2B = c1 ? i1B : (c2 ? si : i2B);
            i1B = c0 ? i0B : (c1 ? si : i1B);
            i0B = c0 ? si : i0B;
            d2B = fminf(fmaxf(d, d1B), d2B);
            d1B = fminf(fmaxf(d, d0B), d1B);
            d0B = fminf(d, d0B);
        }
    }
    {
        int baseA = (slice * 64 + tq) * 3;
        int baseB = (slice * 64 + tq + 32) * 3;
        sD[baseA + 0] = d0A; sD[baseA + 1] = d1A; sD[baseA + 2] = d2A;
        sI[baseA + 0] = i0A; sI[baseA + 1] = i1A; sI[baseA + 2] = i2A;
        sD[baseB + 0] = d0B; sD[baseB + 1] = d1B; sD[baseB + 2] = d2B;
        sI[baseB + 0] = i0B; sI[baseB + 1] = i1B; sI[baseB + 2] = i2B;
    }

    // points1 part: X[j][0:128] = bf16(points1[b][:, n]) (loads done above)
    {
        ushort_t* dstA = X + (size_t)(b * 4096 + n0 + tq) * 512;
        ushort_t* dstB = X + (size_t)(b * 4096 + n0 + tq + 32) * 512;
#pragma unroll
        for (int i = 0; i < 2; ++i) {
            int piece = i * 8 + slice;
            ushort_t tA[8], tB[8];
#pragma unroll
            for (int k = 0; k < 8; ++k) {
                tA[k] = f2b(p1v[i * 8 + k]);
                tB[k] = f2b(p1v[16 + i * 8 + k]);
            }
            *(uint4*)(dstA + piece * 8) = *(const uint4*)tA;
            *(uint4*)(dstB + piece * 8) = *(const uint4*)tB;
        }
    }
    __syncthreads();   // scan + sD/sI complete; sP now dead

    // merge: threads t<64 pick global top-3 of 24 candidates by lex (d, idx).
    if (t < 64) {
        int sel0 = -1, sel1 = -1;
        float seld[3]; int seli[3];
#pragma unroll
        for (int r = 0; r < 3; ++r) {
            float bd = 1e38f; int bi = 1 << 30;
            for (int k = 0; k < 24; ++k) {
                int s3 = (k * 0xAAAB) >> 17;    // k/3 for k<=23
                int rank = k - s3 * 3;
                int base = (s3 * 64 + t) * 3 + rank;
                float cd = sD[base];
                int ci = sI[base];
                bool excl = (ci == sel0) | (ci == sel1);
                bool better = (!excl) & ((cd < bd) | ((cd == bd) & (ci < bi)));
                if (better) { bd = cd; bi = ci; }
            }
            seld[r] = bd; seli[r] = bi;
            if (r == 0) sel0 = bi; else if (r == 1) sel1 = bi;
        }
        float r0 = 1.0f / (seld[0] + 1e-8f);
        float r1 = 1.0f / (seld[1] + 1e-8f);
        float r2 = 1.0f / (seld[2] + 1e-8f);
        float rs = r0 + r1 + r2;
        sw[t * 3 + 0] = r0 / rs; sw[t * 3 + 1] = r1 / rs; sw[t * 3 + 2] = r2 / rs;
        sidx[t * 3 + 0] = seli[0]; sidx[t * 3 + 1] = seli[1]; sidx[t * 3 + 2] = seli[2];
    }
    __syncthreads();

    // gather: 64 queries x 48 pieces = 3072 items
#pragma unroll
    for (int i = 0; i < 12; ++i) {
        int idx = i * 256 + t;
        int q = idx / 48;
        int rem = idx - q * 48;
        int r = rem >> 4;
        int piece = rem & 15;
        int si = sidx[q * 3 + r];
        float wt = sw[q * 3 + r];
        const ushort_t* src = p2t + ((size_t)b * 1024 + si) * 128 + piece * 8;
        uint4 raw = *(const uint4*)src;
        ushort_t* e = (ushort_t*)&raw;
        ushort_t outv[8];
#pragma unroll
        for (int k = 0; k < 8; ++k) outv[k] = f2b(wt * b2f(e[k]));
        ushort_t* dst = X + (size_t)(b * 4096 + n0 + q) * 512 + 128 + r * 128 + piece * 8;
        *(uint4*)dst = *(const uint4*)outv;
    }
}

// ---------------------------------------------------------------------------
// GEMM0: Y[j][o] = sum_k A[o][k]*Bt[j][k] + bias[o], M=256 per block.
// ONE block per j-tile (512 blocks x 512 threads, 8 waves = 4m x 2n,
// per-wave 64x64 acc[4][4]): X staged ONCE (was twice -> ~67MB HBM saved,
// the measured bottleneck; BK halving showed barriers aren't it).
// Exactly 2 blocks/CU resident -> no tail. Epilogue in two m-halves.
__global__ __launch_bounds__(512, 4) void k_gemm(const ushort_t* __restrict__ A,
                                                 const ushort_t* __restrict__ Bt,
                                                 const float* __restrict__ bias,
                                                 ushort_t* __restrict__ Y,
                                                 float* __restrict__ part_s,
                                                 float* __restrict__ part_q,
                                                 int Mtot, int K) {
    __shared__ __align__(16) char smem[51200];
    ushort_t* As = (ushort_t*)smem;               // 256 x 64 bf16 = 32 KB
    ushort_t* Bs = (ushort_t*)(smem + 32768);     // 128 x 64 bf16 = 16 KB
    ushort_t* sY = (ushort_t*)smem;               // 128 x 136 epilogue (34816 B)
    float* red_s = (float*)(smem + 49152);        // 256 floats
    float* red_q = red_s + 256;                   // 256 floats

    int t = threadIdx.x;
    int j0 = blockIdx.x * 128;
    int wave = t >> 6, lane = t & 63;
    int wm = wave >> 1, wn = wave & 1;            // wm 0..3 (m), wn 0..1 (j)
    int l16 = lane & 15, quad = lane >> 4;

    if (t < 256) { red_s[t] = 0.f; red_q[t] = 0.f; }

    f32x4 acc[4][4] = {};

    int nk = K >> 6;
    for (int kt = 0; kt < nk; ++kt) {
#pragma unroll
        for (int c = 0; c < 4; ++c) {
            int idx = c * 512 + t;
            int row = idx >> 3, kc = idx & 7;
            gl_lds16(A + (size_t)row * K + kt * 64 + kc * 8, As + idx * 8);
        }
#pragma unroll
        for (int c = 0; c < 2; ++c) {
            int idx = c * 512 + t;
            int row = idx >> 3, kc = idx & 7;
            gl_lds16(Bt + (size_t)(j0 + row) * K + kt * 64 + kc * 8, Bs + idx * 8);
        }
        __syncthreads();

#pragma unroll
        for (int kk = 0; kk < 2; ++kk) {
            bf16x8 af[4], bfr[4];
#pragma unroll
            for (int mi = 0; mi < 4; ++mi)
                af[mi] = *(const bf16x8*)(As + (wm * 64 + mi * 16 + l16) * 64 + kk * 32 + quad * 8);
#pragma unroll
            for (int ni = 0; ni < 4; ++ni)
                bfr[ni] = *(const bf16x8*)(Bs + (wn * 64 + ni * 16 + l16) * 64 + kk * 32 + quad * 8);
#pragma unroll
            for (int mi = 0; mi < 4; ++mi)
#pragma unroll
                for (int ni = 0; ni < 4; ++ni)
                    acc[mi][ni] = __builtin_amdgcn_mfma_f32_16x16x32_bf16(af[mi], bfr[ni], acc[mi][ni], 0, 0, 0);
        }
        __syncthreads();
    }

    // epilogue: two m-halves through the 128x136 sY staging region
#pragma unroll
    for (int h = 0; h < 2; ++h) {
        if ((wm >> 1) == h) {
#pragma unroll
            for (int mi = 0; mi < 4; ++mi) {
                int obase = wm * 64 + mi * 16 + quad * 4;    // absolute channel
                int ocol = obase - h * 128;                  // 0..124 in half
                float bv[4];
#pragma unroll
                for (int r = 0; r < 4; ++r) bv[r] = bias[obase + r];
                float sr[4] = {0.f, 0.f, 0.f, 0.f}, qr[4] = {0.f, 0.f, 0.f, 0.f};
#pragma unroll
                for (int ni = 0; ni < 4; ++ni) {
                    int j_local = wn * 64 + ni * 16 + l16;
                    ushort4 pk;
                    float v0 = acc[mi][ni][0] + bv[0];
                    float v1 = acc[mi][ni][1] + bv[1];
                    float v2 = acc[mi][ni][2] + bv[2];
                    float v3 = acc[mi][ni][3] + bv[3];
                    pk.x = f2b(v0); pk.y = f2b(v1); pk.z = f2b(v2); pk.w = f2b(v3);
                    sr[0] += v0; qr[0] += v0 * v0;
                    sr[1] += v1; qr[1] += v1 * v1;
                    sr[2] += v2; qr[2] += v2 * v2;
                    sr[3] += v3; qr[3] += v3 * v3;
                    *(ushort4*)(sY + j_local * 136 + ocol) = pk;
                }
#pragma unroll
                for (int r = 0; r < 4; ++r) {
                    float s = sr[r], q = qr[r];
                    s += __shfl_xor(s, 1); s += __shfl_xor(s, 2);
                    s += __shfl_xor(s, 4); s += __shfl_xor(s, 8);
                    q += __shfl_xor(q, 1); q += __shfl_xor(q, 2);
                    q += __shfl_xor(q, 4); q += __shfl_xor(q, 8);
                    if (l16 == 0) {
                        atomicAdd(&red_s[obase + r], s);
                        atomicAdd(&red_q[obase + r], q);
                    }
                }
            }
        }
        __syncthreads();
#pragma unroll
        for (int rep = 0; rep < 4; ++rep) {
            int idx = rep * 512 + t;
            int jl = idx >> 4;
            int o8 = idx & 15;
            uint4 vv = *(const uint4*)(sY + jl * 136 + o8 * 8);
            *(uint4*)(Y + (size_t)(j0 + jl) * Mtot + h * 128 + o8 * 8) = vv;
        }
        __syncthreads();
    }
    if (t < 256) {
        part_s[(size_t)blockIdx.x * Mtot + t] = red_s[t];
        part_q[(size_t)blockIdx.x * Mtot + t] = red_q[t];
    }
}

// ---------------------------------------------------------------------------
// GEMM1 with fused BN0+ReLU applied to the B (Y0) tiles at staging time.
// BK=64 (4 K-steps). sa/sb at 32768 (dead before sY epilogue reuse).
__global__ __launch_bounds__(256) void k_gemmf(const ushort_t* __restrict__ A,
                                               const ushort_t* __restrict__ Y0,
                                               const float* __restrict__ bias,
                                               const float* __restrict__ act_a,
                                               const float* __restrict__ act_b,
                                               ushort_t* __restrict__ Y,
                                               float* __restrict__ part_s,
                                               float* __restrict__ part_q,
                                               int Mtot, int K) {
    __shared__ __align__(16) char smem[35840];
    ushort_t* As = (ushort_t*)smem;               // 128 x 64 = 16 KB
    ushort_t* Bs = (ushort_t*)(smem + 16384);     // 128 x 64 = 16 KB
    float* sa = (float*)(smem + 32768);           // 256 floats
    float* sb = (float*)(smem + 33792);           // 256 floats
    ushort_t* sY = (ushort_t*)smem;               // epilogue reuse
    float* red_s = (float*)(smem + 34816);
    float* red_q = red_s + 128;

    int t = threadIdx.x;
    int m0 = blockIdx.x * 128;
    int j0 = blockIdx.y * 128;
    int wave = t >> 6, lane = t & 63;
    int wm = wave >> 1, wn = wave & 1;
    int l16 = lane & 15, quad = lane >> 4;

    sa[t] = act_a[t]; sb[t] = act_b[t];
    if (t < 128) { red_s[t] = 0.f; red_q[t] = 0.f; }
    __syncthreads();

    f32x4 acc[4][4] = {};

    int nk = K >> 6;
    for (int kt = 0; kt < nk; ++kt) {
#pragma unroll
        for (int c = 0; c < 4; ++c) {
            int idx = c * 256 + t;
            int row = idx >> 3, kc = idx & 7;
            gl_lds16(A + (size_t)(m0 + row) * K + kt * 64 + kc * 8, As + idx * 8);
        }
#pragma unroll
        for (int c = 0; c < 4; ++c) {
            int idx = c * 256 + t;
            int row = idx >> 3, kc = idx & 7;
            int cbase = kt * 64 + kc * 8;
            uint4 raw = *(const uint4*)(Y0 + (size_t)(j0 + row) * K + cbase);
            ushort_t* e = (ushort_t*)&raw;
            ushort_t outv[8];
#pragma unroll
            for (int k = 0; k < 8; ++k) {
                float v = fmaxf(sa[cbase + k] * b2f(e[k]) + sb[cbase + k], 0.f);
                outv[k] = f2b(v);
            }
            *(uint4*)(Bs + idx * 8) = *(const uint4*)outv;
        }
        __syncthreads();

#pragma unroll
        for (int kk = 0; kk < 2; ++kk) {
            bf16x8 af[4], bfr[4];
#pragma unroll
            for (int mi = 0; mi < 4; ++mi)
                af[mi] = *(const bf16x8*)(As + (wm * 64 + mi * 16 + l16) * 64 + kk * 32 + quad * 8);
#pragma unroll
            for (int ni = 0; ni < 4; ++ni)
                bfr[ni] = *(const bf16x8*)(Bs + (wn * 64 + ni * 16 + l16) * 64 + kk * 32 + quad * 8);
#pragma unroll
            for (int mi = 0; mi < 4; ++mi)
#pragma unroll
                for (int ni = 0; ni < 4; ++ni)
                    acc[mi][ni] = __builtin_amdgcn_mfma_f32_16x16x32_bf16(af[mi], bfr[ni], acc[mi][ni], 0, 0, 0);
        }
        __syncthreads();
    }

#pragma unroll
    for (int mi = 0; mi < 4; ++mi) {
        int obase = wm * 64 + mi * 16 + quad * 4;
        float bv[4];
#pragma unroll
        for (int r = 0; r < 4; ++r) bv[r] = bias[m0 + obase + r];
        float sr[4] = {0.f, 0.f, 0.f, 0.f}, qr[4] = {0.f, 0.f, 0.f, 0.f};
#pragma unroll
        for (int ni = 0; ni < 4; ++ni) {
            int j_local = wn * 64 + ni * 16 + l16;
            ushort4 pk;
            float v0 = acc[mi][ni][0] + bv[0];
            float v1 = acc[mi][ni][1] + bv[1];
            float v2 = acc[mi][ni][2] + bv[2];
            float v3 = acc[mi][ni][3] + bv[3];
            pk.x = f2b(v0); pk.y = f2b(v1); pk.z = f2b(v2); pk.w = f2b(v3);
            sr[0] += v0; qr[0] += v0 * v0;
            sr[1] += v1; qr[1] += v1 * v1;
            sr[2] += v2; qr[2] += v2 * v2;
            sr[3] += v3; qr[3] += v3 * v3;
            *(ushort4*)(sY + j_local * 136 + obase) = pk;
        }
#pragma unroll
        for (int r = 0; r < 4; ++r) {
            float s = sr[r], q = qr[r];
            s += __shfl_xor(s, 1); s += __shfl_xor(s, 2);
            s += __shfl_xor(s, 4); s += __shfl_xor(s, 8);
            q += __shfl_xor(q, 1); q += __shfl_xor(q, 2);
            q += __shfl_xor(q, 4); q += __shfl_xor(q, 8);
            if (l16 == 0) {
                atomicAdd(&red_s[obase + r], s);
                atomicAdd(&red_q[obase + r], q);
            }
        }
    }
    __syncthreads();

#pragma unroll
    for (int rep = 0; rep < 8; ++rep) {
        int idx = rep * 256 + t;
        int jl = idx >> 4;
        int o8 = idx & 15;
        uint4 vv = *(const uint4*)(sY + jl * 136 + o8 * 8);
        *(uint4*)(Y + (size_t)(j0 + jl) * Mtot + m0 + o8 * 8) = vv;
    }
    if (t < 128) {
        part_s[(size_t)blockIdx.y * Mtot + m0 + t] = red_s[t];
        part_q[(size_t)blockIdx.y * Mtot + m0 + t] = red_q[t];
    }
}

// ---------------------------------------------------------------------------
// Parallel BN finalize: one block per channel. Fixed-order tree: deterministic.
__global__ __launch_bounds__(256) void k_bnfin(const float* __restrict__ part_s,
                                               const float* __restrict__ part_q,
                                               int nby,
                                               const float* __restrict__ gamma,
                                               const float* __restrict__ beta,
                                               float* __restrict__ a, float* __restrict__ bb,
                                               int C, float inv_count) {
    __shared__ float rs[4], rq[4];
    int i = blockIdx.x;      // channel
    int t = threadIdx.x;
    float s = 0.f, q = 0.f;
    for (int by = t; by < nby; by += 256) {
        s += part_s[(size_t)by * C + i];
        q += part_q[(size_t)by * C + i];
    }
    s += __shfl_xor(s, 1);  q += __shfl_xor(q, 1);
    s += __shfl_xor(s, 2);  q += __shfl_xor(q, 2);
    s += __shfl_xor(s, 4);  q += __shfl_xor(q, 4);
    s += __shfl_xor(s, 8);  q += __shfl_xor(q, 8);
    s += __shfl_xor(s, 16); q += __shfl_xor(q, 16);
    s += __shfl_xor(s, 32); q += __shfl_xor(q, 32);
    int wv = t >> 6, ln = t & 63;
    if (ln == 0) { rs[wv] = s; rq[wv] = q; }
    __syncthreads();
    if (t == 0) {
        s = (rs[0] + rs[1]) + (rs[2] + rs[3]);
        q = (rq[0] + rq[1]) + (rq[2] + rq[3]);
        float mean = s * inv_count;
        float var = q * inv_count - mean * mean;
        float sc = gamma[i] / sqrtf(var + 1e-5f);
        a[i] = sc;
        bb[i] = beta[i] - mean * sc;
    }
}

// ---------------------------------------------------------------------------
__global__ __launch_bounds__(256) void k_out(const ushort_t* __restrict__ Y1,
                                             const float* __restrict__ a,
                                             const float* __restrict__ bb,
                                             float* __restrict__ out) {
    __shared__ float sa[128], sb[128];
    int t = threadIdx.x;
    if (t < 128) { sa[t] = a[t]; sb[t] = bb[t]; }
    __syncthreads();
    int b = blockIdx.x;
    int nl = t & 127;
    int half = t >> 7;
    int n = blockIdx.y * 128 + nl;
    const uint4* src = (const uint4*)(Y1 + (size_t)(b * 4096 + n) * 128);
    float* dst = out + (size_t)b * 128 * 4096 + n;
    uint4 raw[8];
#pragma unroll
    for (int p = 0; p < 8; ++p) raw[p] = src[half * 8 + p];
    const ushort_t* e = (const ushort_t*)raw;
#pragma unroll
    for (int c = 0; c < 64; ++c) {
        int ch = half * 64 + c;
        float v = b2f(e[c]);
        v = fmaxf(sa[ch] * v + sb[ch], 0.f);
        dst[(size_t)ch * 4096] = v;
    }
}

// ---------------------------------------------------------------------------
extern "C" void kernel_launch(void* const* d_in, const int* in_sizes, int n_in,
                              void* d_out, int out_size, void* d_ws, size_t ws_size,
                              hipStream_t stream) {
    const float* xyz1    = (const float*)d_in[0];
    const float* xyz2    = (const float*)d_in[1];
    const float* points1 = (const float*)d_in[2];
    const float* points2 = (const float*)d_in[3];
    const float* w0      = (const float*)d_in[4];
    const float* b0      = (const float*)d_in[5];
    const float* gamma0  = (const float*)d_in[6];
    const float* beta0   = (const float*)d_in[7];
    const float* w1      = (const float*)d_in[8];
    const float* b1      = (const float*)d_in[9];
    const float* gamma1  = (const float*)d_in[10];
    const float* beta1   = (const float*)d_in[11];
    float* out = (float*)d_out;

    char* ws = (char*)d_ws;
    const size_t OFF_X    = 0;                       // 67108864
    const size_t OFF_Y0   = 67108864;                // 33554432
    const size_t OFF_Y1   = 100663296;               // 16777216
    const size_t OFF_P2T  = 117440512;               // 4194304
    const size_t OFF_W0B  = 121634816;               // 262144
    const size_t OFF_W1B  = 121896960;               // 65536
    const size_t OFF_AB   = 121962496;               // 3072
    const size_t OFF_SDAT = 121965568;               // 262144
    const size_t OFF_PS0  = 122227712;               // 524288
    const size_t OFF_PQ0  = 122752000;               // 524288
    const size_t OFF_PS1  = 123276288;               // 262144
    const size_t OFF_PQ1  = 123538432;               // 262144

    ushort_t* X    = (ushort_t*)(ws + OFF_X);
    ushort_t* Y0   = (ushort_t*)(ws + OFF_Y0);
    ushort_t* Y1   = (ushort_t*)(ws + OFF_Y1);
    ushort_t* p2t  = (ushort_t*)(ws + OFF_P2T);
    ushort_t* w0b  = (ushort_t*)(ws + OFF_W0B);
    ushort_t* w1b  = (ushort_t*)(ws + OFF_W1B);
    float* ab      = (float*)(ws + OFF_AB);
    float4* sdat   = (float4*)(ws + OFF_SDAT);
    float* ps0 = (float*)(ws + OFF_PS0);
    float* pq0 = (float*)(ws + OFF_PQ0);
    float* ps1 = (float*)(ws + OFF_PS1);
    float* pq1 = (float*)(ws + OFF_PQ1);
    float* a0 = ab;       float* bb0 = ab + 256;
    float* a1 = ab + 512; float* bb1 = ab + 640;

    k_pre<<<960, 256, 0, stream>>>(w0, w0b, w1, w1b, xyz2, sdat, points2, p2t);
    k_interp<<<dim3(16, 64), 256, 0, stream>>>(xyz1, sdat, points1, p2t, X);
    k_gemm<<<512, 512, 0, stream>>>(w0b, X, b0, Y0, ps0, pq0, 256, 512);
    k_bnfin<<<256, 256, 0, stream>>>(ps0, pq0, 512, gamma0, beta0, a0, bb0, 256, 1.0f / 65536.0f);
    k_gemmf<<<dim3(1, 512), 256, 0, stream>>>(w1b, Y0, b1, a0, bb0, Y1, ps1, pq1, 128, 256);
    k_bnfin<<<128, 256, 0, stream>>>(ps1, pq1, 512, gamma1, beta1, a1, bb1, 128, 1.0f / 65536.0f);
    k_out<<<dim3(16, 32), 256, 0, stream>>>(Y1, a1, bb1, out);
}